// Round 14
// baseline (1634.725 us; speedup 1.0000x reference)
//
#include <hip/hip_runtime.h>

#define NN 2048
#define NE 32768
#define NG 64
#define DINJ 240
#define DEMB 480
#define DFEAT 512
#define MAXDEG 192

typedef unsigned short ushort_t;
typedef __attribute__((ext_vector_type(8))) short short8;
typedef __attribute__((ext_vector_type(4))) float floatx4;

__device__ __forceinline__ float b2f(ushort_t u){
  union { unsigned u; float f; } x; x.u = ((unsigned)u) << 16; return x.f;
}
__device__ __forceinline__ ushort_t f2b(float f){
  union { float f; unsigned u; } x; x.f = f;
  unsigned r = x.u + 0x7FFFu + ((x.u >> 16) & 1u);
  return (ushort_t)(r >> 16);
}
__device__ __forceinline__ unsigned pk2(float a, float b){
  return (__float_as_uint(a) >> 16) | (__float_as_uint(b) & 0xFFFF0000u);
}
__device__ __forceinline__ float wredsum(float v){
  #pragma unroll
  for (int o = 32; o > 0; o >>= 1) v += __shfl_xor(v, o, 64);
  return v;
}
__device__ __forceinline__ float silu_f(float x){ return x / (1.f + __expf(-x)); }

// ---------------- small utility kernels ----------------
__global__ void zero_f32(float* p, int n){
  int i = blockIdx.x*256 + threadIdx.x; if (i < n) p[i] = 0.f;
}

// ---------------- input dtype detection ----------------
__global__ void detect_kernel(const ushort_t* __restrict__ probe, int* flag){
  __shared__ int c;
  if (threadIdx.x == 0) c = 0;
  __syncthreads();
  ushort_t u = probe[2*threadIdx.x];
  int e = (u >> 7) & 0xFF;
  int plausible = (u == 0) || (e >= 100 && e <= 140);
  atomicAdd(&c, plausible);
  __syncthreads();
  if (threadIdx.x == 0) *flag = (c >= 192) ? 0 : 1;
}

// -------- convert small float inputs -> internal FP32 (exact either way) ----
struct CDesc { const void* src; float* dst; int n; };
struct CDescArr { CDesc d[11]; };
__global__ __launch_bounds__(256) void convert_inputs(CDescArr ca, const int* __restrict__ flag){
  CDesc cd = ca.d[blockIdx.y];
  int isf32 = *flag;
  for (int i = blockIdx.x*256 + threadIdx.x; i < cd.n; i += gridDim.x*256){
    cd.dst[i] = isf32 ? ((const float*)cd.src)[i] : b2f(((const ushort_t*)cd.src)[i]);
  }
}

// --- LDS-tiled weight transpose: src (K x M row-major) -> dst (Mpad x Kpad) --
struct TDesc { const void* src; ushort_t* dh; ushort_t* dl; int K; int M; int Kpad; int Mpad; int eoff; };
struct TDescArr { TDesc d[37]; };
__global__ __launch_bounds__(256) void transpose_all(TDescArr ta, const int* __restrict__ flag){
  TDesc td = ta.d[blockIdx.z];
  int k0 = blockIdx.x*32, m0 = blockIdx.y*32;
  if (k0 >= td.Kpad || m0 >= td.Mpad) return;
  int isf32 = *flag;
  __shared__ float lds[32*33];
  int tx = threadIdx.x & 31, ty = threadIdx.x >> 5;
  #pragma unroll
  for (int r = 0; r < 4; ++r){
    int kl = ty + r*8;
    int k = k0 + kl, mm = m0 + tx;
    float x = 0.f;
    if (k < td.K && mm < td.M){
      size_t si = (size_t)td.eoff + (size_t)k*td.M + mm;
      x = isf32 ? ((const float*)td.src)[si] : b2f(((const ushort_t*)td.src)[si]);
    }
    lds[kl*33 + tx] = x;
  }
  __syncthreads();
  #pragma unroll
  for (int r = 0; r < 4; ++r){
    int nl = ty + r*8;
    int n = m0 + nl, k = k0 + tx;
    if (n < td.Mpad && k < td.Kpad){
      float x = lds[tx*33 + nl];
      ushort_t h = f2b(x);
      size_t di = (size_t)n*td.Kpad + k;
      td.dh[di] = h;
      td.dl[di] = f2b(x - b2f(h));
    }
  }
}

// ---- pack 6 Wr slots into Wr_all[128][24] ----------------------------------
__global__ void pack_wr(const float* __restrict__ b0Wr, const float* __restrict__ bmWr,
                        const float* __restrict__ bfWr, float* __restrict__ Wr_all){
  int idx = blockIdx.x*256 + threadIdx.x; if (idx >= 128*24) return;
  int k = idx / 24, o = idx - k*24;
  int slot = o >> 2, h = o & 3;
  const float* Wr = (slot == 0) ? b0Wr : ((slot <= 4) ? bmWr + (size_t)(slot-1)*512 : bfWr);
  Wr_all[idx] = Wr[k*4+h];
}

// ---- fused per-edge setup: LDS-staged weights, 128-thread blocks ------------
__global__ __launch_bounds__(128) void edge_all_kernel(
    const float* __restrict__ pos,
    const int* __restrict__ esrc, const int* __restrict__ edst,
    const float* __restrict__ degWr, const float* __restrict__ Wr_all,
    float* __restrict__ sh_out, float* __restrict__ t9,
    float* __restrict__ r_all){
  __shared__ float w9L[128*9];
  __shared__ float w24L[128*24];
  int t = threadIdx.x;
  for (int i = t; i < 128*9; i += 128)  w9L[i]  = degWr[i];
  for (int i = t; i < 128*24; i += 128) w24L[i] = Wr_all[i];
  __syncthreads();
  int e = blockIdx.x*128 + t; if (e >= NE) return;
  int s = esrc[e], d = edst[e];
  float x = pos[s*3+0] - pos[d*3+0];
  float y = pos[s*3+1] - pos[d*3+1];
  float z = pos[s*3+2] - pos[d*3+2];
  float dd = sqrtf(x*x + y*y + z*z + 1e-12f);
  float ix = x/dd, iy = y/dd, iz = z/dd;
  const float s3 = 1.7320508075688772f, s15 = 3.872983346207417f, s5 = 2.23606797749979f;
  float sh[9];
  sh[0] = 1.f; sh[1] = s3*ix; sh[2] = s3*iy; sh[3] = s3*iz;
  sh[4] = s15*ix*iy; sh[5] = s15*iy*iz; sh[6] = 0.5f*s5*(3.f*iz*iz - 1.f);
  sh[7] = s15*ix*iz; sh[8] = 0.5f*s15*(ix*ix - iy*iy);
  #pragma unroll
  for (int j = 0; j < 9; ++j) sh_out[(size_t)e*9+j] = sh[j];
  float t9a[9], ga[24];
  #pragma unroll
  for (int j = 0; j < 9; ++j) t9a[j] = 0.f;
  #pragma unroll
  for (int o = 0; o < 24; ++o) ga[o] = 0.f;
  for (int k = 0; k < 128; ++k){
    float c = (float)k * (5.0f/127.0f);
    float u = (dd - c) * (128.0f/5.0f);
    float rb = __expf(-0.5f*u*u);
    const float* w9  = w9L + k*9;
    const float* w24 = w24L + k*24;
    #pragma unroll
    for (int j = 0; j < 9; ++j) t9a[j] += rb*w9[j];
    #pragma unroll
    for (int o = 0; o < 24; ++o) ga[o] += rb*w24[o];
  }
  #pragma unroll
  for (int j = 0; j < 9; ++j) t9[(size_t)e*9+j] = sh[j]*silu_f(t9a[j]);
  #pragma unroll
  for (int o = 0; o < 24; ++o){
    int slot = o >> 2, h = o & 3;
    r_all[((size_t)slot*NE + e)*4 + h] = silu_f(ga[o]);
  }
}

// ---------------- CSR build ----------------
__global__ void hist_kernel(const int* __restrict__ edst, int* counts){
  int e = blockIdx.x*256 + threadIdx.x; if (e < NE) atomicAdd(&counts[edst[e]], 1);
}
__global__ __launch_bounds__(1024) void scan_kernel(const int* __restrict__ counts,
                                                    int* rowptr, int* cursor){
  __shared__ int s[1024];
  int t = threadIdx.x;
  int c0 = counts[2*t], c1 = counts[2*t+1];
  s[t] = c0 + c1;
  __syncthreads();
  for (int off = 1; off < 1024; off <<= 1){
    int v = (t >= off) ? s[t-off] : 0;
    __syncthreads();
    s[t] += v;
    __syncthreads();
  }
  int excl = s[t] - (c0 + c1);
  rowptr[2*t]   = excl;       cursor[2*t]   = excl;
  rowptr[2*t+1] = excl + c0;  cursor[2*t+1] = excl + c0;
  if (t == 1023) rowptr[2048] = s[1023];
}
__global__ void scatter_kernel(const int* __restrict__ edst, int* cursor, int* perm){
  int e = blockIdx.x*256 + threadIdx.x; if (e >= NE) return;
  int p = atomicAdd(&cursor[edst[e]], 1);
  perm[p] = e;
}

// -- inj = atom_table[node_atom] + (sum_e t9) @ degWsh / 16, + row stats ------
__global__ __launch_bounds__(64) void inj_kernel(const float* __restrict__ t9,
    const int* __restrict__ rowptr, const int* __restrict__ perm,
    const int* __restrict__ node_atom, const float* __restrict__ atom_table,
    const float* __restrict__ degWsh, float* __restrict__ inj,
    float* __restrict__ injS){
  int i = blockIdx.x; int lane = threadIdx.x;
  int b = rowptr[i], e = rowptr[i+1];
  float T[9];
  #pragma unroll
  for (int j = 0; j < 9; ++j) T[j] = 0.f;
  for (int idx = b; idx < e; ++idx){
    int ed = perm[idx];
    #pragma unroll
    for (int j = 0; j < 9; ++j) T[j] += t9[(size_t)ed*9+j];
  }
  int a = node_atom[i];
  float ps = 0.f, pq = 0.f;
  for (int c = lane; c < DINJ; c += 64){
    float s = 0.f;
    #pragma unroll
    for (int j = 0; j < 9; ++j) s += T[j]*degWsh[j*DINJ+c];
    float v = atom_table[(size_t)a*DINJ+c] + s*(1.0f/16.0f);
    inj[(size_t)i*DINJ+c] = v;
    ps += v; pq += v*v;
  }
  ps = wredsum(ps); pq = wredsum(pq);
  if (lane == 0){ injS[i*2] = ps; injS[i*2+1] = pq; }
}

// -- MFMA GEMM with optional fused input-LN (A raw fp32 + producer stats) and
//    optional fused output-stats (partial row sum/sumsq per 32-col slot).
// LNA: 0 = A is bf16 (stride KPAD); 1 = A raw fp32 (Din wide) + LN; 2 = concat
//      [z(480)|inj(240)] fp32 + LN over 720.
// flags: 1=silu, 2=add residual, 4=bf16 out, 8=residual concat(R 480, R2 240)
template<int KPAD, bool SPLITB, int LNA, bool STATS>
__global__ __launch_bounds__(256) void gemm_bt(
    const void* __restrict__ Abuf, const float* __restrict__ Ainj,
    const float* __restrict__ injS,
    const float* __restrict__ stIn, int stInStride, int nslots, int Din,
    const ushort_t* __restrict__ BTh, const ushort_t* __restrict__ BTl,
    int N, int ldc,
    float* __restrict__ Cf, ushort_t* __restrict__ Cb,
    const float* __restrict__ R, const float* __restrict__ R2,
    float* __restrict__ stOut, int stOutStride, int flags){
  int lane = threadIdx.x & 63, wave = threadIdx.x >> 6;
  int row0 = blockIdx.y*64 + (wave>>1)*32;
  int col0 = blockIdx.x*64 + (wave&1)*32;
  int m = lane & 15, q4 = lane >> 4;
  size_t b0 = (size_t)(col0+m)*KPAD + q4*8;
  size_t b1 = b0 + (size_t)16*KPAD;
  int r0 = row0 + m, r1 = row0 + 16 + m;
  // A access setup
  const ushort_t* A16 = (const ushort_t*)Abuf;
  const float*    A32 = (const float*)Abuf;
  size_t a0 = 0, a1 = 0;
  const float *az0 = nullptr, *az1 = nullptr, *aj0 = nullptr, *aj1 = nullptr;
  float rs0 = 0.f, nm0 = 0.f, rs1 = 0.f, nm1 = 0.f;
  if constexpr (LNA == 0){
    a0 = (size_t)r0*KPAD + q4*8;
    a1 = (size_t)r1*KPAD + q4*8;
  } else {
    int zw = (LNA == 2) ? 480 : Din;
    az0 = A32 + (size_t)r0*zw;
    az1 = A32 + (size_t)r1*zw;
    if constexpr (LNA == 2){
      aj0 = Ainj + (size_t)r0*240;
      aj1 = Ainj + (size_t)r1*240;
    }
    float DD = (LNA == 2) ? 720.f : (float)Din;
    #pragma unroll
    for (int which = 0; which < 2; ++which){
      int row = which ? r1 : r0;
      float s = 0.f, q = 0.f;
      const float* st = stIn + (size_t)row*stInStride;
      for (int t2 = 0; t2 < nslots; ++t2){ s += st[2*t2]; q += st[2*t2+1]; }
      if constexpr (LNA == 2){ s += injS[row*2]; q += injS[row*2+1]; }
      float mu = s / DD;
      float var = fmaxf(q / DD - mu*mu, 0.f);
      float rs = rsqrtf(var + 1e-6f);
      float nm = -mu*rs;
      if (which){ rs1 = rs; nm1 = nm; } else { rs0 = rs; nm0 = nm; }
    }
  }
  auto loadAfrag = [&](int s, int which) -> short8 {
    if constexpr (LNA == 0){
      size_t base = which ? a1 : a0;
      return *(const short8*)(A16 + base + (size_t)s*32);
    } else {
      int k = q4*8 + s*32;
      float x[8];
      const float* az = which ? az1 : az0;
      bool zero = false;
      if constexpr (LNA == 1){
        if (k < Din){
          float4 p = *(const float4*)(az + k);
          float4 q2 = *(const float4*)(az + k + 4);
          x[0]=p.x; x[1]=p.y; x[2]=p.z; x[3]=p.w;
          x[4]=q2.x; x[5]=q2.y; x[6]=q2.z; x[7]=q2.w;
        } else zero = true;
      } else {
        if (k < 480){
          float4 p = *(const float4*)(az + k);
          float4 q2 = *(const float4*)(az + k + 4);
          x[0]=p.x; x[1]=p.y; x[2]=p.z; x[3]=p.w;
          x[4]=q2.x; x[5]=q2.y; x[6]=q2.z; x[7]=q2.w;
        } else if (k < 720){
          const float* aj = which ? aj1 : aj0;
          float4 p = *(const float4*)(aj + (k - 480));
          float4 q2 = *(const float4*)(aj + (k - 480) + 4);
          x[0]=p.x; x[1]=p.y; x[2]=p.z; x[3]=p.w;
          x[4]=q2.x; x[5]=q2.y; x[6]=q2.z; x[7]=q2.w;
        } else zero = true;
      }
      union { short8 v; unsigned u[4]; } o;
      if (zero){
        o.u[0] = o.u[1] = o.u[2] = o.u[3] = 0u;
      } else {
        float rs = which ? rs1 : rs0;
        float nm = which ? nm1 : nm0;
        #pragma unroll
        for (int p2 = 0; p2 < 4; ++p2){
          float f0 = fmaf(x[2*p2],   rs, nm);
          float f1 = fmaf(x[2*p2+1], rs, nm);
          o.u[p2] = pk2(f0, f1);
        }
      }
      return o.v;
    }
  };
  floatx4 acc00 = {0,0,0,0}, acc01 = {0,0,0,0}, acc10 = {0,0,0,0}, acc11 = {0,0,0,0};
  constexpr int steps = KPAD >> 5;
  constexpr int DEPTH = SPLITB ? 3 : 4;
  struct Frag { short8 A0, A1, B0h, B1h, B0l, B1l; };
  auto loadF = [&](int s) -> Frag {
    Frag f;
    size_t o = (size_t)s*32;
    f.A0  = loadAfrag(s, 0);
    f.A1  = loadAfrag(s, 1);
    f.B0h = *(const short8*)(BTh + b0 + o);
    f.B1h = *(const short8*)(BTh + b1 + o);
    if (SPLITB){
      f.B0l = *(const short8*)(BTl + b0 + o);
      f.B1l = *(const short8*)(BTl + b1 + o);
    }
    return f;
  };
  Frag ring[DEPTH];
  #pragma unroll
  for (int d = 0; d < DEPTH; ++d) ring[d] = loadF(d < steps ? d : steps-1);
  #pragma unroll
  for (int s = 0; s < steps; ++s){
    Frag cur = ring[s % DEPTH];
    if (s + DEPTH < steps) ring[s % DEPTH] = loadF(s + DEPTH);
    acc00 = __builtin_amdgcn_mfma_f32_16x16x32_bf16(cur.A0, cur.B0h, acc00, 0, 0, 0);
    acc01 = __builtin_amdgcn_mfma_f32_16x16x32_bf16(cur.A0, cur.B1h, acc01, 0, 0, 0);
    acc10 = __builtin_amdgcn_mfma_f32_16x16x32_bf16(cur.A1, cur.B0h, acc10, 0, 0, 0);
    acc11 = __builtin_amdgcn_mfma_f32_16x16x32_bf16(cur.A1, cur.B1h, acc11, 0, 0, 0);
    if (SPLITB){
      acc00 = __builtin_amdgcn_mfma_f32_16x16x32_bf16(cur.A0, cur.B0l, acc00, 0, 0, 0);
      acc01 = __builtin_amdgcn_mfma_f32_16x16x32_bf16(cur.A0, cur.B1l, acc01, 0, 0, 0);
      acc10 = __builtin_amdgcn_mfma_f32_16x16x32_bf16(cur.A1, cur.B0l, acc10, 0, 0, 0);
      acc11 = __builtin_amdgcn_mfma_f32_16x16x32_bf16(cur.A1, cur.B1l, acc11, 0, 0, 0);
    }
  }
  // epilogue
  float vf[2][2][4];
  #pragma unroll
  for (int rr = 0; rr < 2; ++rr){
    #pragma unroll
    for (int cc = 0; cc < 2; ++cc){
      int col = col0 + cc*16 + m;
      bool cv = (col < N);
      floatx4 acc = rr ? (cc ? acc11 : acc10) : (cc ? acc01 : acc00);
      int rowb = row0 + rr*16 + q4*4;
      #pragma unroll
      for (int r = 0; r < 4; ++r){
        float v = 0.f;
        if (cv){
          int row = rowb + r;
          size_t idx = (size_t)row*ldc + col;
          v = acc[r];
          if (flags & 2){
            if (flags & 8)
              v += (col < 480) ? R[(size_t)row*480 + col] : R2[(size_t)row*240 + (col-480)];
            else
              v += R[idx];
          }
          if (flags & 1) v = silu_f(v);
          if (flags & 4) Cb[idx] = f2b(v);
          else           Cf[idx] = v;
        }
        vf[rr][cc][r] = v;
      }
    }
  }
  if constexpr (STATS){
    int slot = blockIdx.x*2 + (wave & 1);
    #pragma unroll
    for (int rr = 0; rr < 2; ++rr){
      #pragma unroll
      for (int r = 0; r < 4; ++r){
        float sm = vf[rr][0][r] + vf[rr][1][r];
        float sq = vf[rr][0][r]*vf[rr][0][r] + vf[rr][1][r]*vf[rr][1][r];
        #pragma unroll
        for (int o2 = 1; o2 < 16; o2 <<= 1){
          sm += __shfl_xor(sm, o2, 64);
          sq += __shfl_xor(sq, o2, 64);
        }
        if (m == 0){
          int row = row0 + rr*16 + q4*4 + r;
          stOut[(size_t)row*stOutStride + slot*2]     = sm;
          stOut[(size_t)row*stOutStride + slot*2 + 1] = sq;
        }
      }
    }
  }
}

// ------- fused per-node attention: logits + softmax + aggregation ------------
__global__ __launch_bounds__(256) void node_attn_kernel(
    const float* __restrict__ qkv, const float* __restrict__ sh,
    const float* __restrict__ Wsh, const float* __restrict__ r_slot,
    const int* __restrict__ rowptr, const int* __restrict__ perm,
    const int* __restrict__ esrc, ushort_t* __restrict__ aggh){
  int i = blockIdx.x; int t = threadIdx.x;
  int lane = t & 63, w = t >> 6;
  int b = rowptr[i]; int deg = min(rowptr[i+1] - b, MAXDEG);
  __shared__ float qL[480];
  __shared__ float PqL[36];
  __shared__ float logitL[MAXDEG*4];
  __shared__ float rL[MAXDEG*4];
  __shared__ int eL[MAXDEG], srcL[MAXDEG];
  __shared__ float S[36];
  __shared__ float mxs[4], dens[4];
  for (int d = t; d < 480; d += 256) qL[d] = qkv[(size_t)i*1440 + d];
  for (int idx = t; idx < deg; idx += 256){
    int e = perm[b+idx];
    eL[idx] = e;
    srcL[idx] = esrc[e];
  }
  __syncthreads();
  if (t < 36){
    int h = t/9, j = t - h*9;
    const float* ws = Wsh + (size_t)j*DEMB + h*120;
    const float* qh = qL + h*120;
    float p = 0.f;
    for (int k = 0; k < 120; ++k) p += qh[k]*ws[k];
    PqL[t] = p;
  }
  __syncthreads();
  const float inv = 0.091287092917527686f;
  for (int base = 0; base < deg; base += 64){
    int idx = base + (t >> 2);
    if (idx < deg){
      int h = t & 3;
      int e = eL[idx], s = srcL[idx];
      const float4* kk = (const float4*)(qkv + (size_t)s*1440 + 480 + h*120);
      const float4* qq = (const float4*)(qL + h*120);
      float p = 0.f;
      #pragma unroll
      for (int it = 0; it < 30; ++it){
        float4 a = qq[it], bb = kk[it];
        p += a.x*bb.x + a.y*bb.y + a.z*bb.z + a.w*bb.w;
      }
      float mmq = 0.f;
      const float* she = sh + (size_t)e*9;
      #pragma unroll
      for (int j = 0; j < 9; ++j) mmq += she[j]*PqL[h*9+j];
      float rr = r_slot[(size_t)e*4+h];
      rL[idx*4+h] = rr;
      logitL[idx*4+h] = rr*(p + mmq)*inv;
    }
  }
  __syncthreads();
  float mx = -1e30f;
  for (int idx = lane; idx < deg; idx += 64) mx = fmaxf(mx, logitL[idx*4+w]);
  #pragma unroll
  for (int o = 32; o > 0; o >>= 1) mx = fmaxf(mx, __shfl_xor(mx, o, 64));
  if (deg == 0) mx = 0.f;
  float den = 0.f;
  for (int idx = lane; idx < deg; idx += 64) den += __expf(logitL[idx*4+w]-mx);
  den = wredsum(den) + 1e-9f;
  if (lane == 0){ mxs[w] = mx; dens[w] = den; }
  __syncthreads();
  for (int j = t; j < deg*4; j += 256){
    int h = j & 3;
    logitL[j] = __expf(logitL[j]-mxs[h]) / dens[h] * rL[j];
  }
  __syncthreads();
  float a0 = 0.f, a1 = 0.f;
  int d0 = 2*t, h2 = d0/120;
  if (t >= 240){
    for (int o = t - 240; o < 36; o += 16){
      int h = o/9, j = o - h*9;
      float a = 0.f;
      for (int idx = 0; idx < deg; ++idx)
        a += logitL[idx*4+h]*sh[(size_t)eL[idx]*9+j];
      S[o] = a;
    }
  } else {
    for (int idx = 0; idx < deg; ++idx){
      float wgt = logitL[idx*4+h2];
      float2 vv = *(const float2*)(qkv + (size_t)srcL[idx]*1440 + 960 + d0);
      a0 += wgt*vv.x; a1 += wgt*vv.y;
    }
  }
  __syncthreads();
  if (t < 240){
    float mm0 = 0.f, mm1 = 0.f;
    #pragma unroll
    for (int j = 0; j < 9; ++j){
      mm0 += S[h2*9+j]*Wsh[j*DEMB + d0];
      mm1 += S[h2*9+j]*Wsh[j*DEMB + d0 + 1];
    }
    aggh[(size_t)i*DEMB + d0]     = f2b(a0 + mm0);
    aggh[(size_t)i*DEMB + d0 + 1] = f2b(a1 + mm1);
  }
}

// ---------------- head ----------------
__global__ __launch_bounds__(256) void head_dot_kernel(const ushort_t* __restrict__ g1h,
    const float* __restrict__ hW2, const int* __restrict__ batch, float* gsum){
  int i = blockIdx.x*4 + (threadIdx.x >> 6);
  int lane = threadIdx.x & 63;
  float s = 0.f;
  for (int d = lane; d < DFEAT; d += 64)
    s += b2f(g1h[(size_t)i*DFEAT + d]) * hW2[d];
  s = wredsum(s);
  if (lane == 0) atomicAdd(&gsum[batch[i]], s);
}
__global__ void finalize_kernel(const float* __restrict__ gsum,
                                const int* __restrict__ flag, void* out){
  int g = threadIdx.x;
  if (g < NG){
    float v = gsum[g] * 0.17677669529663687f; // 1/sqrt(32)
    if (*flag) ((float*)out)[g] = v;
    else       ((ushort_t*)out)[g] = f2b(v);
  }
}

// =====================================================================
extern "C" void kernel_launch(void* const* d_in, const int* in_sizes, int n_in,
                              void* d_out, int out_size, void* d_ws, size_t ws_size,
                              hipStream_t stream) {
  (void)in_sizes; (void)n_in; (void)out_size; (void)ws_size;
  const void* pos        = d_in[0];
  const int*  node_atom  = (const int*)d_in[1];
  const int*  esrc       = (const int*)d_in[2];
  const int*  edst       = (const int*)d_in[3];
  const int*  batch      = (const int*)d_in[4];
  const void* atom_table = d_in[5];
  const void* degWr      = d_in[6];
  const void* degWsh     = d_in[7];
  const void* b0_Wq  = d_in[8];
  const void* b0_Wk  = d_in[9];
  const void* b0_Wv  = d_in[10];
  const void* b0_Wsh = d_in[11];
  const void* b0_Wr  = d_in[12];
  const void* b0_Wo  = d_in[13];
  const void* b0_F1  = d_in[14];
  const void* b0_F2  = d_in[15];
  const void* bm_Wq  = d_in[16];
  const void* bm_Wk  = d_in[17];
  const void* bm_Wv  = d_in[18];
  const void* bm_Wsh = d_in[19];
  const void* bm_Wr  = d_in[20];
  const void* bm_Wo  = d_in[21];
  const void* bm_F1  = d_in[22];
  const void* bm_F2  = d_in[23];
  const void* bf_Wq  = d_in[24];
  const void* bf_Wk  = d_in[25];
  const void* bf_Wv  = d_in[26];
  const void* bf_Wsh = d_in[27];
  const void* bf_Wr  = d_in[28];
  const void* bf_Wo  = d_in[29];
  const void* bf_F1  = d_in[30];
  const void* bf_F2  = d_in[31];
  const void* hW1    = d_in[32];
  const void* hW2    = d_in[33];

  char* bws = (char*)d_ws;
  size_t off = 0;
  auto alloc = [&](size_t bytes) -> void* {
    void* p = bws + off;
    off += (bytes + 255) & ~(size_t)255;
    return p;
  };
  int* dflag   = (int*)alloc(256);
  float* sh_f  = (float*)alloc((size_t)NE*9*4);
  float* t9    = (float*)alloc((size_t)NE*9*4);
  int* counts  = (int*)alloc(2048*4);
  int* rowptr  = (int*)alloc(2049*4);
  int* cursor  = (int*)alloc(2048*4);
  int* perm    = (int*)alloc((size_t)NE*4);
  float* injb  = (float*)alloc((size_t)NN*DINJ*4);
  float* injS  = (float*)alloc((size_t)NN*2*4);
  // zA followed contiguously by its stats (one zero fill covers both)
  float* zA    = (float*)alloc((size_t)NN*512*4);
  float* stZA  = (float*)alloc((size_t)NN*32*4);
  float* zB    = (float*)alloc((size_t)NN*512*4);
  float* stZB  = (float*)alloc((size_t)NN*32*4);
  float* stY   = (float*)alloc((size_t)NN*48*4);
  float* qkvb  = (float*)alloc((size_t)NN*1440*4);
  float* Wr_all = (float*)alloc((size_t)128*24*4);
  float* r_all = (float*)alloc((size_t)6*NE*4*4);
  ushort_t* aggh = (ushort_t*)alloc((size_t)NN*DEMB*2);
  float* ybuf  = (float*)alloc((size_t)NN*720*4);
  ushort_t* h1h = (ushort_t*)alloc((size_t)NN*DEMB*2);
  ushort_t* g1h = (ushort_t*)alloc((size_t)NN*DFEAT*2);
  float* gsum  = (float*)alloc(64*4);

  float* pos_c    = (float*)alloc((size_t)NN*3*4);
  float* atom_c   = (float*)alloc((size_t)64*DINJ*4);
  float* degWr_c  = (float*)alloc((size_t)128*9*4);
  float* degWsh_c = (float*)alloc((size_t)9*DINJ*4);
  float* b0_Wsh_c = (float*)alloc((size_t)9*480*4);
  float* b0_Wr_c  = (float*)alloc((size_t)128*4*4);
  float* bm_Wsh_c = (float*)alloc((size_t)4*9*480*4);
  float* bm_Wr_c  = (float*)alloc((size_t)4*128*4*4);
  float* bf_Wsh_c = (float*)alloc((size_t)9*480*4);
  float* bf_Wr_c  = (float*)alloc((size_t)128*4*4);
  float* hW2_c    = (float*)alloc((size_t)512*4);

  auto allocW = [&](size_t elems, ushort_t*& h, ushort_t*& l){
    h = (ushort_t*)alloc(elems*2); l = (ushort_t*)alloc(elems*2);
  };
  ushort_t *b0_qkvTh,*b0_qkvTl,*b0_WoTh,*b0_WoTl,*b0_F1Th,*b0_F1Tl,*b0_F2Th,*b0_F2Tl;
  allocW((size_t)1472*736, b0_qkvTh, b0_qkvTl);
  allocW((size_t)768*480,  b0_WoTh,  b0_WoTl);
  allocW((size_t)512*736,  b0_F1Th,  b0_F1Tl);
  allocW((size_t)512*480,  b0_F2Th,  b0_F2Tl);
  ushort_t *bm_qkvTh[4],*bm_qkvTl[4],*bm_WoTh[4],*bm_WoTl[4],*bm_F1Th[4],*bm_F1Tl[4],*bm_F2Th[4],*bm_F2Tl[4];
  for (int i = 0; i < 4; ++i){
    allocW((size_t)1472*480, bm_qkvTh[i], bm_qkvTl[i]);
    allocW((size_t)512*480,  bm_WoTh[i],  bm_WoTl[i]);
    allocW((size_t)512*480,  bm_F1Th[i],  bm_F1Tl[i]);
    allocW((size_t)512*480,  bm_F2Th[i],  bm_F2Tl[i]);
  }
  ushort_t *bf_qkvTh,*bf_qkvTl,*bf_WoTh,*bf_WoTl,*bf_F1Th,*bf_F1Tl,*bf_F2Th,*bf_F2Tl,*hW1Th,*hW1Tl;
  allocW((size_t)1472*480, bf_qkvTh, bf_qkvTl);
  allocW((size_t)512*480,  bf_WoTh,  bf_WoTl);
  allocW((size_t)512*480,  bf_F1Th,  bf_F1Tl);
  allocW((size_t)512*480,  bf_F2Th,  bf_F2Tl);
  allocW((size_t)512*512,  hW1Th,    hW1Tl);

  detect_kernel<<<1, 256, 0, stream>>>((const ushort_t*)atom_table, dflag);

  CDescArr ca;
  int ci = 0;
  auto addC = [&](const void* s, float* d, int n){
    ca.d[ci].src = s; ca.d[ci].dst = d; ca.d[ci].n = n; ++ci;
  };
  addC(pos, pos_c, NN*3);
  addC(atom_table, atom_c, 64*DINJ);
  addC(degWr, degWr_c, 128*9);
  addC(degWsh, degWsh_c, 9*DINJ);
  addC(b0_Wsh, b0_Wsh_c, 9*480);
  addC(b0_Wr, b0_Wr_c, 128*4);
  addC(bm_Wsh, bm_Wsh_c, 4*9*480);
  addC(bm_Wr, bm_Wr_c, 4*128*4);
  addC(bf_Wsh, bf_Wsh_c, 9*480);
  addC(bf_Wr, bf_Wr_c, 128*4);
  addC(hW2, hW2_c, 512);
  convert_inputs<<<dim3(8, 11), 256, 0, stream>>>(ca, dflag);

  TDescArr ta;
  int ti = 0;
  auto addT = [&](const void* s, ushort_t* dh, ushort_t* dl, int K, int M,
                  int Kp, int Mp, int rowoff, int eo){
    ta.d[ti].src = s;
    ta.d[ti].dh = dh + (size_t)rowoff*Kp;
    ta.d[ti].dl = dl + (size_t)rowoff*Kp;
    ta.d[ti].K = K; ta.d[ti].M = M; ta.d[ti].Kpad = Kp; ta.d[ti].Mpad = Mp;
    ta.d[ti].eoff = eo; ++ti;
  };
  addT(b0_Wq, b0_qkvTh, b0_qkvTl, 720, 480, 736, 480, 0,   0);
  addT(b0_Wk, b0_qkvTh, b0_qkvTl, 720, 480, 736, 480, 480, 0);
  addT(b0_Wv, b0_qkvTh, b0_qkvTl, 720, 480, 736, 512, 960, 0);
  addT(b0_Wo, b0_WoTh,  b0_WoTl,  480, 720, 480, 768, 0,   0);
  addT(b0_F1, b0_F1Th,  b0_F1Tl,  720, 480, 736, 512, 0,   0);
  addT(b0_F2, b0_F2Th,  b0_F2Tl,  480, 480, 480, 512, 0,   0);
  for (int i = 0; i < 4; ++i){
    int eo = i*480*480;
    addT(bm_Wq, bm_qkvTh[i], bm_qkvTl[i], 480, 480, 480, 480, 0,   eo);
    addT(bm_Wk, bm_qkvTh[i], bm_qkvTl[i], 480, 480, 480, 480, 480, eo);
    addT(bm_Wv, bm_qkvTh[i], bm_qkvTl[i], 480, 480, 480, 512, 960, eo);
    addT(bm_Wo, bm_WoTh[i],  bm_WoTl[i],  480, 480, 480, 512, 0,   eo);
    addT(bm_F1, bm_F1Th[i],  bm_F1Tl[i],  480, 480, 480, 512, 0,   eo);
    addT(bm_F2, bm_F2Th[i],  bm_F2Tl[i],  480, 480, 480, 512, 0,   eo);
  }
  addT(bf_Wq, bf_qkvTh, bf_qkvTl, 480, 480, 480, 480, 0,   0);
  addT(bf_Wk, bf_qkvTh, bf_qkvTl, 480, 480, 480, 480, 480, 0);
  addT(bf_Wv, bf_qkvTh, bf_qkvTl, 480, 480, 480, 512, 960, 0);
  addT(bf_Wo, bf_WoTh,  bf_WoTl,  480, 480, 480, 512, 0,   0);
  addT(bf_F1, bf_F1Th,  bf_F1Tl,  480, 480, 480, 512, 0,   0);
  addT(bf_F2, bf_F2Th,  bf_F2Tl,  480, 512, 480, 512, 0,   0);
  addT(hW1,   hW1Th,    hW1Tl,    512, 512, 512, 512, 0,   0);
  transpose_all<<<dim3(23, 24, 37), 256, 0, stream>>>(ta, dflag);

  pack_wr<<<12, 256, 0, stream>>>(b0_Wr_c, bm_Wr_c, bf_Wr_c, Wr_all);
  edge_all_kernel<<<NE/128, 128, 0, stream>>>(pos_c, esrc, edst, degWr_c, Wr_all,
                                              sh_f, t9, r_all);

  zero_f32<<<(2048 + 255)/256, 256, 0, stream>>>((float*)counts, 2048);
  hist_kernel<<<NE/256, 256, 0, stream>>>(edst, counts);
  scan_kernel<<<1, 1024, 0, stream>>>(counts, rowptr, cursor);
  scatter_kernel<<<NE/256, 256, 0, stream>>>(edst, cursor, perm);

  inj_kernel<<<NN, 64, 0, stream>>>(t9, rowptr, perm, node_atom, atom_c, degWsh_c,
                                    injb, injS);
  // zero zA and its stats (contiguous)
  zero_f32<<<(NN*544 + 255)/256, 256, 0, stream>>>(zA, NN*544);

  struct BW {
    const float *Wsh, *r_slot;
    const ushort_t *qkvTh,*qkvTl,*WoTh,*WoTl,*F1Th,*F1Tl,*F2Th,*F2Tl;
    int Din, Dout; bool res;
  };
  // zinj != null -> b0 block (concat input, KPAD=736)
  auto run_block = [&](const BW& bw, const float* zin, float* zinStats,
                       const float* zinj, float* zout, float* zoutStats){
    if (zinj){
      gemm_bt<736,true,2,false><<<dim3(23,32), 256, 0, stream>>>(
        zin, zinj, injS, zinStats, 32, 16, 720,
        bw.qkvTh, bw.qkvTl, 1440, 1440, qkvb, nullptr,
        nullptr, nullptr, nullptr, 0, 0);
    } else {
      gemm_bt<480,true,1,false><<<dim3(23,32), 256, 0, stream>>>(
        zin, nullptr, nullptr, zinStats, 32, 16, 480,
        bw.qkvTh, bw.qkvTl, 1440, 1440, qkvb, nullptr,
        nullptr, nullptr, nullptr, 0, 0);
    }
    node_attn_kernel<<<NN, 256, 0, stream>>>(qkvb, sh_f, bw.Wsh, bw.r_slot,
                                             rowptr, perm, esrc, aggh);
    int WoNpad = (bw.Din == 720) ? 768 : 512;
    gemm_bt<480,false,0,true><<<dim3(WoNpad/64,32), 256, 0, stream>>>(
      aggh, nullptr, nullptr, nullptr, 0, 0, 0,
      bw.WoTh, bw.WoTl, bw.Din, bw.Din, ybuf, nullptr,
      zin, zinj, stY, 48, zinj ? (2|8) : 2);
    if (bw.Din == 720){
      gemm_bt<736,false,1,false><<<dim3(8,32), 256, 0, stream>>>(
        ybuf, nullptr, nullptr, stY, 48, 24, 720,
        bw.F1Th, bw.F1Tl, 480, 480, nullptr, h1h,
        nullptr, nullptr, nullptr, 0, 1|4);
    } else {
      gemm_bt<480,false,1,false><<<dim3(8,32), 256, 0, stream>>>(
        ybuf, nullptr, nullptr, stY, 48, 16, 480,
        bw.F1Th, bw.F1Tl, 480, 480, nullptr, h1h,
        nullptr, nullptr, nullptr, 0, 1|4);
    }
    gemm_bt<480,false,0,true><<<dim3(8,32), 256, 0, stream>>>(
      h1h, nullptr, nullptr, nullptr, 0, 0, 0,
      bw.F2Th, bw.F2Tl, bw.Dout, bw.Dout, zout, nullptr,
      bw.res ? ybuf : nullptr, nullptr, zoutStats, 32, bw.res ? 2 : 0);
  };

  BW b0 = { b0_Wsh_c, r_all + (size_t)0*NE*4,
            b0_qkvTh,b0_qkvTl,b0_WoTh,b0_WoTl,b0_F1Th,b0_F1Tl,b0_F2Th,b0_F2Tl,
            720, 480, false };
  BW bm[4];
  for (int i = 0; i < 4; ++i){
    bm[i] = { bm_Wsh_c + (size_t)i*9*480, r_all + (size_t)(1+i)*NE*4,
              bm_qkvTh[i],bm_qkvTl[i],bm_WoTh[i],bm_WoTl[i],
              bm_F1Th[i],bm_F1Tl[i],bm_F2Th[i],bm_F2Tl[i],
              480, 480, true };
  }
  BW bf = { bf_Wsh_c, r_all + (size_t)5*NE*4,
            bf_qkvTh,bf_qkvTl,bf_WoTh,bf_WoTl,bf_F1Th,bf_F1Tl,bf_F2Th,bf_F2Tl,
            480, 512, false };

  float* z  = zA;  float* zS  = stZA;
  float* z2 = zB;  float* z2S = stZB;
  for (int iter = 0; iter < 2; ++iter){
    run_block(b0, z, zS, injb, z2, z2S);
    { float* t1 = z; z = z2; z2 = t1; float* t2 = zS; zS = z2S; z2S = t2; }
    for (int i = 0; i < 4; ++i){
      run_block(bm[i], z, zS, nullptr, z2, z2S);
      { float* t1 = z; z = z2; z2 = t1; float* t2 = zS; zS = z2S; z2S = t2; }
    }
  }
  run_block(bf, z, zS, nullptr, z2, z2S);
  // head: hW1 with fused LN over feat (512-wide, stats in z2S)
  gemm_bt<512,true,1,false><<<dim3(8,32), 256, 0, stream>>>(
    z2, nullptr, nullptr, z2S, 32, 16, 512,
    hW1Th, hW1Tl, 512, 512, nullptr, g1h,
    nullptr, nullptr, nullptr, 0, 1|4);
  zero_f32<<<1, 64, 0, stream>>>(gsum, 64);
  head_dot_kernel<<<NN/4, 256, 0, stream>>>(g1h, hW2_c, batch, gsum);
  finalize_kernel<<<1, 64, 0, stream>>>(gsum, dflag, d_out);
}

// Round 15
// 1407.707 us; speedup vs baseline: 1.1613x; 1.1613x over previous
//
#include <hip/hip_runtime.h>

#define NN 2048
#define NE 32768
#define NG 64
#define DINJ 240
#define DEMB 480
#define DFEAT 512
#define MAXDEG 192

typedef unsigned short ushort_t;
typedef __attribute__((ext_vector_type(8))) short short8;
typedef __attribute__((ext_vector_type(4))) float floatx4;

__device__ __forceinline__ float b2f(ushort_t u){
  union { unsigned u; float f; } x; x.u = ((unsigned)u) << 16; return x.f;
}
__device__ __forceinline__ ushort_t f2b(float f){
  union { float f; unsigned u; } x; x.f = f;
  unsigned r = x.u + 0x7FFFu + ((x.u >> 16) & 1u);
  return (ushort_t)(r >> 16);
}
__device__ __forceinline__ float wredsum(float v){
  #pragma unroll
  for (int o = 32; o > 0; o >>= 1) v += __shfl_xor(v, o, 64);
  return v;
}
__device__ __forceinline__ float silu_f(float x){ return x / (1.f + __expf(-x)); }

// ---------------- small utility kernels ----------------
__global__ void zero_f32(float* p, int n){
  int i = blockIdx.x*256 + threadIdx.x; if (i < n) p[i] = 0.f;
}

// ---------------- input dtype detection ----------------
__global__ void detect_kernel(const ushort_t* __restrict__ probe, int* flag){
  __shared__ int c;
  if (threadIdx.x == 0) c = 0;
  __syncthreads();
  ushort_t u = probe[2*threadIdx.x];
  int e = (u >> 7) & 0xFF;
  int plausible = (u == 0) || (e >= 100 && e <= 140);
  atomicAdd(&c, plausible);
  __syncthreads();
  if (threadIdx.x == 0) *flag = (c >= 192) ? 0 : 1;
}

// -------- convert small float inputs -> internal FP32 (exact either way) ----
struct CDesc { const void* src; float* dst; int n; };
struct CDescArr { CDesc d[11]; };
__global__ __launch_bounds__(256) void convert_inputs(CDescArr ca, const int* __restrict__ flag){
  CDesc cd = ca.d[blockIdx.y];
  int isf32 = *flag;
  for (int i = blockIdx.x*256 + threadIdx.x; i < cd.n; i += gridDim.x*256){
    cd.dst[i] = isf32 ? ((const float*)cd.src)[i] : b2f(((const ushort_t*)cd.src)[i]);
  }
}

// --- LDS-tiled weight transpose: src (K x M row-major) -> dst (Mpad x Kpad) --
struct TDesc { const void* src; ushort_t* dh; ushort_t* dl; int K; int M; int Kpad; int Mpad; int eoff; };
struct TDescArr { TDesc d[37]; };
__global__ __launch_bounds__(256) void transpose_all(TDescArr ta, const int* __restrict__ flag){
  TDesc td = ta.d[blockIdx.z];
  int k0 = blockIdx.x*32, m0 = blockIdx.y*32;
  if (k0 >= td.Kpad || m0 >= td.Mpad) return;
  int isf32 = *flag;
  __shared__ float lds[32*33];
  int tx = threadIdx.x & 31, ty = threadIdx.x >> 5;
  #pragma unroll
  for (int r = 0; r < 4; ++r){
    int kl = ty + r*8;
    int k = k0 + kl, mm = m0 + tx;
    float x = 0.f;
    if (k < td.K && mm < td.M){
      size_t si = (size_t)td.eoff + (size_t)k*td.M + mm;
      x = isf32 ? ((const float*)td.src)[si] : b2f(((const ushort_t*)td.src)[si]);
    }
    lds[kl*33 + tx] = x;
  }
  __syncthreads();
  #pragma unroll
  for (int r = 0; r < 4; ++r){
    int nl = ty + r*8;
    int n = m0 + nl, k = k0 + tx;
    if (n < td.Mpad && k < td.Kpad){
      float x = lds[tx*33 + nl];
      ushort_t h = f2b(x);
      size_t di = (size_t)n*td.Kpad + k;
      td.dh[di] = h;
      td.dl[di] = f2b(x - b2f(h));
    }
  }
}

// ---- pack 6 Wr slots into Wr_all[128][24] (k-major, o=slot*4+h inner) ------
__global__ void pack_wr(const float* __restrict__ b0Wr, const float* __restrict__ bmWr,
                        const float* __restrict__ bfWr, float* __restrict__ Wr_all){
  int idx = blockIdx.x*256 + threadIdx.x; if (idx >= 128*24) return;
  int k = idx / 24, o = idx - k*24;
  int slot = o >> 2, h = o & 3;
  const float* Wr = (slot == 0) ? b0Wr : ((slot <= 4) ? bmWr + (size_t)(slot-1)*512 : bfWr);
  Wr_all[idx] = Wr[k*4+h];
}

// ---- fused per-edge setup: geometry + sh + t9 + all 6 gate slots ------------
__global__ __launch_bounds__(256) void edge_all_kernel(
    const float* __restrict__ pos,
    const int* __restrict__ esrc, const int* __restrict__ edst,
    const float* __restrict__ degWr, const float* __restrict__ Wr_all,
    float* __restrict__ sh_out, float* __restrict__ t9,
    float* __restrict__ r_all){
  int e = blockIdx.x*256 + threadIdx.x; if (e >= NE) return;
  int s = esrc[e], d = edst[e];
  float x = pos[s*3+0] - pos[d*3+0];
  float y = pos[s*3+1] - pos[d*3+1];
  float z = pos[s*3+2] - pos[d*3+2];
  float dd = sqrtf(x*x + y*y + z*z + 1e-12f);
  float ix = x/dd, iy = y/dd, iz = z/dd;
  const float s3 = 1.7320508075688772f, s15 = 3.872983346207417f, s5 = 2.23606797749979f;
  float sh[9];
  sh[0] = 1.f; sh[1] = s3*ix; sh[2] = s3*iy; sh[3] = s3*iz;
  sh[4] = s15*ix*iy; sh[5] = s15*iy*iz; sh[6] = 0.5f*s5*(3.f*iz*iz - 1.f);
  sh[7] = s15*ix*iz; sh[8] = 0.5f*s15*(ix*ix - iy*iy);
  #pragma unroll
  for (int j = 0; j < 9; ++j) sh_out[(size_t)e*9+j] = sh[j];
  float t9a[9], ga[24];
  #pragma unroll
  for (int j = 0; j < 9; ++j) t9a[j] = 0.f;
  #pragma unroll
  for (int o = 0; o < 24; ++o) ga[o] = 0.f;
  for (int k = 0; k < 128; ++k){
    float c = (float)k * (5.0f/127.0f);
    float u = (dd - c) * (128.0f/5.0f);
    float rb = __expf(-0.5f*u*u);
    const float* w9  = degWr + k*9;
    const float* w24 = Wr_all + k*24;
    #pragma unroll
    for (int j = 0; j < 9; ++j) t9a[j] += rb*w9[j];
    #pragma unroll
    for (int o = 0; o < 24; ++o) ga[o] += rb*w24[o];
  }
  #pragma unroll
  for (int j = 0; j < 9; ++j) t9[(size_t)e*9+j] = sh[j]*silu_f(t9a[j]);
  #pragma unroll
  for (int o = 0; o < 24; ++o){
    int slot = o >> 2, h = o & 3;
    r_all[((size_t)slot*NE + e)*4 + h] = silu_f(ga[o]);
  }
}

// ---------------- CSR build ----------------
__global__ void hist_kernel(const int* __restrict__ edst, int* counts){
  int e = blockIdx.x*256 + threadIdx.x; if (e < NE) atomicAdd(&counts[edst[e]], 1);
}
__global__ __launch_bounds__(1024) void scan_kernel(const int* __restrict__ counts,
                                                    int* rowptr, int* cursor){
  __shared__ int s[1024];
  int t = threadIdx.x;
  int c0 = counts[2*t], c1 = counts[2*t+1];
  s[t] = c0 + c1;
  __syncthreads();
  for (int off = 1; off < 1024; off <<= 1){
    int v = (t >= off) ? s[t-off] : 0;
    __syncthreads();
    s[t] += v;
    __syncthreads();
  }
  int excl = s[t] - (c0 + c1);
  rowptr[2*t]   = excl;       cursor[2*t]   = excl;
  rowptr[2*t+1] = excl + c0;  cursor[2*t+1] = excl + c0;
  if (t == 1023) rowptr[2048] = s[1023];
}
__global__ void scatter_kernel(const int* __restrict__ edst, int* cursor, int* perm){
  int e = blockIdx.x*256 + threadIdx.x; if (e >= NE) return;
  int p = atomicAdd(&cursor[edst[e]], 1);
  perm[p] = e;
}

// ---------------- inj = atom_table[node_atom] + (sum_e t9) @ degWsh / 16 -----
__global__ __launch_bounds__(64) void inj_kernel(const float* __restrict__ t9,
    const int* __restrict__ rowptr, const int* __restrict__ perm,
    const int* __restrict__ node_atom, const float* __restrict__ atom_table,
    const float* __restrict__ degWsh, float* __restrict__ inj){
  int i = blockIdx.x; int lane = threadIdx.x;
  int b = rowptr[i], e = rowptr[i+1];
  float T[9];
  #pragma unroll
  for (int j = 0; j < 9; ++j) T[j] = 0.f;
  for (int idx = b; idx < e; ++idx){
    int ed = perm[idx];
    #pragma unroll
    for (int j = 0; j < 9; ++j) T[j] += t9[(size_t)ed*9+j];
  }
  int a = node_atom[i];
  for (int c = lane; c < DINJ; c += 64){
    float s = 0.f;
    #pragma unroll
    for (int j = 0; j < 9; ++j) s += T[j]*degWsh[j*DINJ+c];
    inj[(size_t)i*DINJ+c] = atom_table[(size_t)a*DINJ+c] + s*(1.0f/16.0f);
  }
}

// ------- LayerNorm: one wave per row, 4 rows per block -----------------------
__global__ __launch_bounds__(256) void ln_kernel(const float* __restrict__ in, int D,
                                                 int Kpad, ushort_t* __restrict__ oh){
  int i = blockIdx.x*4 + (threadIdx.x >> 6);
  int lane = threadIdx.x & 63;
  const float* row = in + (size_t)i*D;
  float s = 0.f, sq = 0.f;
  for (int d = lane; d < D; d += 64){ float x = row[d]; s += x; sq += x*x; }
  s = wredsum(s); sq = wredsum(sq);
  float mu = s / (float)D;
  float var = fmaxf(sq / (float)D - mu*mu, 0.f);
  float rs = rsqrtf(var + 1e-6f);
  ushort_t* ohrow = oh + (size_t)i*Kpad;
  for (int d = lane; d < D; d += 64) ohrow[d] = f2b((row[d]-mu)*rs);
  for (int d = D + lane; d < Kpad; d += 64) ohrow[d] = 0;
}

// ------- LayerNorm over concat [z(480) | inj(240)] -> 736-padded bf16 --------
__global__ __launch_bounds__(256) void ln_cat_kernel(const float* __restrict__ z,
    const float* __restrict__ inj, ushort_t* __restrict__ oh){
  int i = blockIdx.x*4 + (threadIdx.x >> 6);
  int lane = threadIdx.x & 63;
  const float* zr = z + (size_t)i*480;
  const float* ir = inj + (size_t)i*240;
  float s = 0.f, sq = 0.f;
  for (int d = lane; d < 720; d += 64){
    float x = (d < 480) ? zr[d] : ir[d-480];
    s += x; sq += x*x;
  }
  s = wredsum(s); sq = wredsum(sq);
  float mu = s * (1.0f/720.0f);
  float var = fmaxf(sq * (1.0f/720.0f) - mu*mu, 0.f);
  float rs = rsqrtf(var + 1e-6f);
  ushort_t* ohrow = oh + (size_t)i*736;
  for (int d = lane; d < 720; d += 64){
    float x = (d < 480) ? zr[d] : ir[d-480];
    ohrow[d] = f2b((x-mu)*rs);
  }
  for (int d = 720 + lane; d < 736; d += 64) ohrow[d] = 0;
}

// -- MFMA GEMM: C = A * B^T with B = Bh (+Bl if SPLITB). Ring prefetch. -------
// flags: 1=silu, 2=add residual, 4=bf16 out, 8=residual is concat(R 480, R2 240)
template<int KPAD, bool SPLITB>
__global__ __launch_bounds__(256) void gemm_bt(
    const ushort_t* __restrict__ A,
    const ushort_t* __restrict__ BTh, const ushort_t* __restrict__ BTl,
    int N, int ldc,
    float* __restrict__ Cf, ushort_t* __restrict__ Cb,
    const float* __restrict__ R, const float* __restrict__ R2, int flags){
  int lane = threadIdx.x & 63, wave = threadIdx.x >> 6;
  int row0 = blockIdx.y*64 + (wave>>1)*32;
  int col0 = blockIdx.x*64 + (wave&1)*32;
  int m = lane & 15, q4 = lane >> 4;
  size_t a0 = (size_t)(row0+m)*KPAD + q4*8;
  size_t a1 = a0 + (size_t)16*KPAD;
  size_t b0 = (size_t)(col0+m)*KPAD + q4*8;
  size_t b1 = b0 + (size_t)16*KPAD;
  floatx4 acc00 = {0,0,0,0}, acc01 = {0,0,0,0}, acc10 = {0,0,0,0}, acc11 = {0,0,0,0};
  constexpr int steps = KPAD >> 5;
  constexpr int DEPTH = SPLITB ? 3 : 4;
  struct Frag { short8 A0, A1, B0h, B1h, B0l, B1l; };
  auto loadF = [&](int s) -> Frag {
    Frag f;
    size_t o = (size_t)s*32;
    f.A0  = *(const short8*)(A   + a0 + o);
    f.A1  = *(const short8*)(A   + a1 + o);
    f.B0h = *(const short8*)(BTh + b0 + o);
    f.B1h = *(const short8*)(BTh + b1 + o);
    if (SPLITB){
      f.B0l = *(const short8*)(BTl + b0 + o);
      f.B1l = *(const short8*)(BTl + b1 + o);
    }
    return f;
  };
  Frag ring[DEPTH];
  #pragma unroll
  for (int d = 0; d < DEPTH; ++d) ring[d] = loadF(d < steps ? d : steps-1);
  #pragma unroll
  for (int s = 0; s < steps; ++s){
    Frag cur = ring[s % DEPTH];
    if (s + DEPTH < steps) ring[s % DEPTH] = loadF(s + DEPTH);
    acc00 = __builtin_amdgcn_mfma_f32_16x16x32_bf16(cur.A0, cur.B0h, acc00, 0, 0, 0);
    acc01 = __builtin_amdgcn_mfma_f32_16x16x32_bf16(cur.A0, cur.B1h, acc01, 0, 0, 0);
    acc10 = __builtin_amdgcn_mfma_f32_16x16x32_bf16(cur.A1, cur.B0h, acc10, 0, 0, 0);
    acc11 = __builtin_amdgcn_mfma_f32_16x16x32_bf16(cur.A1, cur.B1h, acc11, 0, 0, 0);
    if (SPLITB){
      acc00 = __builtin_amdgcn_mfma_f32_16x16x32_bf16(cur.A0, cur.B0l, acc00, 0, 0, 0);
      acc01 = __builtin_amdgcn_mfma_f32_16x16x32_bf16(cur.A0, cur.B1l, acc01, 0, 0, 0);
      acc10 = __builtin_amdgcn_mfma_f32_16x16x32_bf16(cur.A1, cur.B0l, acc10, 0, 0, 0);
      acc11 = __builtin_amdgcn_mfma_f32_16x16x32_bf16(cur.A1, cur.B1l, acc11, 0, 0, 0);
    }
  }
  #pragma unroll
  for (int rr = 0; rr < 2; ++rr){
    #pragma unroll
    for (int cc = 0; cc < 2; ++cc){
      int col = col0 + cc*16 + m;
      if (col >= N) continue;
      floatx4 acc = rr ? (cc ? acc11 : acc10) : (cc ? acc01 : acc00);
      int rowb = row0 + rr*16 + q4*4;
      #pragma unroll
      for (int r = 0; r < 4; ++r){
        int row = rowb + r;
        size_t idx = (size_t)row*ldc + col;
        float v = acc[r];
        if (flags & 2){
          if (flags & 8)
            v += (col < 480) ? R[(size_t)row*480 + col] : R2[(size_t)row*240 + (col-480)];
          else
            v += R[idx];
        }
        if (flags & 1) v = silu_f(v);
        if (flags & 4) Cb[idx] = f2b(v);
        else           Cf[idx] = v;
      }
    }
  }
}

// ------- fused per-node attention: logits + softmax + aggregation ------------
__global__ __launch_bounds__(256) void node_attn_kernel(
    const float* __restrict__ qkv, const float* __restrict__ sh,
    const float* __restrict__ Wsh, const float* __restrict__ r_slot,
    const int* __restrict__ rowptr, const int* __restrict__ perm,
    const int* __restrict__ esrc, ushort_t* __restrict__ aggh){
  int i = blockIdx.x; int t = threadIdx.x;
  int lane = t & 63, w = t >> 6;
  int b = rowptr[i]; int deg = min(rowptr[i+1] - b, MAXDEG);
  __shared__ float qL[480];
  __shared__ float PqL[36];
  __shared__ float logitL[MAXDEG*4];
  __shared__ float rL[MAXDEG*4];
  __shared__ int eL[MAXDEG], srcL[MAXDEG];
  __shared__ float S[36];
  __shared__ float mxs[4], dens[4];
  for (int d = t; d < 480; d += 256) qL[d] = qkv[(size_t)i*1440 + d];
  for (int idx = t; idx < deg; idx += 256){
    int e = perm[b+idx];
    eL[idx] = e;
    srcL[idx] = esrc[e];
  }
  __syncthreads();
  if (t < 36){
    int h = t/9, j = t - h*9;
    const float* ws = Wsh + (size_t)j*DEMB + h*120;
    const float* qh = qL + h*120;
    float p = 0.f;
    for (int k = 0; k < 120; ++k) p += qh[k]*ws[k];
    PqL[t] = p;
  }
  __syncthreads();
  const float inv = 0.091287092917527686f;
  for (int base = 0; base < deg; base += 64){
    int idx = base + (t >> 2);
    if (idx < deg){
      int h = t & 3;
      int e = eL[idx], s = srcL[idx];
      const float4* kk = (const float4*)(qkv + (size_t)s*1440 + 480 + h*120);
      const float4* qq = (const float4*)(qL + h*120);
      float p = 0.f;
      #pragma unroll
      for (int it = 0; it < 30; ++it){
        float4 a = qq[it], bb = kk[it];
        p += a.x*bb.x + a.y*bb.y + a.z*bb.z + a.w*bb.w;
      }
      float mmq = 0.f;
      const float* she = sh + (size_t)e*9;
      #pragma unroll
      for (int j = 0; j < 9; ++j) mmq += she[j]*PqL[h*9+j];
      float rr = r_slot[(size_t)e*4+h];
      rL[idx*4+h] = rr;
      logitL[idx*4+h] = rr*(p + mmq)*inv;
    }
  }
  __syncthreads();
  float mx = -1e30f;
  for (int idx = lane; idx < deg; idx += 64) mx = fmaxf(mx, logitL[idx*4+w]);
  #pragma unroll
  for (int o = 32; o > 0; o >>= 1) mx = fmaxf(mx, __shfl_xor(mx, o, 64));
  if (deg == 0) mx = 0.f;
  float den = 0.f;
  for (int idx = lane; idx < deg; idx += 64) den += __expf(logitL[idx*4+w]-mx);
  den = wredsum(den) + 1e-9f;
  if (lane == 0){ mxs[w] = mx; dens[w] = den; }
  __syncthreads();
  for (int j = t; j < deg*4; j += 256){
    int h = j & 3;
    logitL[j] = __expf(logitL[j]-mxs[h]) / dens[h] * rL[j];
  }
  __syncthreads();
  float a0 = 0.f, a1 = 0.f;
  int d0 = 2*t, h2 = d0/120;
  if (t >= 240){
    for (int o = t - 240; o < 36; o += 16){
      int h = o/9, j = o - h*9;
      float a = 0.f;
      for (int idx = 0; idx < deg; ++idx)
        a += logitL[idx*4+h]*sh[(size_t)eL[idx]*9+j];
      S[o] = a;
    }
  } else {
    for (int idx = 0; idx < deg; ++idx){
      float wgt = logitL[idx*4+h2];
      float2 vv = *(const float2*)(qkv + (size_t)srcL[idx]*1440 + 960 + d0);
      a0 += wgt*vv.x; a1 += wgt*vv.y;
    }
  }
  __syncthreads();
  if (t < 240){
    float mm0 = 0.f, mm1 = 0.f;
    #pragma unroll
    for (int j = 0; j < 9; ++j){
      mm0 += S[h2*9+j]*Wsh[j*DEMB + d0];
      mm1 += S[h2*9+j]*Wsh[j*DEMB + d0 + 1];
    }
    aggh[(size_t)i*DEMB + d0]     = f2b(a0 + mm0);
    aggh[(size_t)i*DEMB + d0 + 1] = f2b(a1 + mm1);
  }
}

// ---------------- head ----------------
__global__ __launch_bounds__(256) void head_dot_kernel(const ushort_t* __restrict__ g1h,
    const float* __restrict__ hW2, const int* __restrict__ batch, float* gsum){
  int i = blockIdx.x*4 + (threadIdx.x >> 6);
  int lane = threadIdx.x & 63;
  float s = 0.f;
  for (int d = lane; d < DFEAT; d += 64)
    s += b2f(g1h[(size_t)i*DFEAT + d]) * hW2[d];
  s = wredsum(s);
  if (lane == 0) atomicAdd(&gsum[batch[i]], s);
}
__global__ void finalize_kernel(const float* __restrict__ gsum,
                                const int* __restrict__ flag, void* out){
  int g = threadIdx.x;
  if (g < NG){
    float v = gsum[g] * 0.17677669529663687f; // 1/sqrt(32)
    if (*flag) ((float*)out)[g] = v;
    else       ((ushort_t*)out)[g] = f2b(v);
  }
}

// =====================================================================
extern "C" void kernel_launch(void* const* d_in, const int* in_sizes, int n_in,
                              void* d_out, int out_size, void* d_ws, size_t ws_size,
                              hipStream_t stream) {
  (void)in_sizes; (void)n_in; (void)out_size; (void)ws_size;
  const void* pos        = d_in[0];
  const int*  node_atom  = (const int*)d_in[1];
  const int*  esrc       = (const int*)d_in[2];
  const int*  edst       = (const int*)d_in[3];
  const int*  batch      = (const int*)d_in[4];
  const void* atom_table = d_in[5];
  const void* degWr      = d_in[6];
  const void* degWsh     = d_in[7];
  const void* b0_Wq  = d_in[8];
  const void* b0_Wk  = d_in[9];
  const void* b0_Wv  = d_in[10];
  const void* b0_Wsh = d_in[11];
  const void* b0_Wr  = d_in[12];
  const void* b0_Wo  = d_in[13];
  const void* b0_F1  = d_in[14];
  const void* b0_F2  = d_in[15];
  const void* bm_Wq  = d_in[16];
  const void* bm_Wk  = d_in[17];
  const void* bm_Wv  = d_in[18];
  const void* bm_Wsh = d_in[19];
  const void* bm_Wr  = d_in[20];
  const void* bm_Wo  = d_in[21];
  const void* bm_F1  = d_in[22];
  const void* bm_F2  = d_in[23];
  const void* bf_Wq  = d_in[24];
  const void* bf_Wk  = d_in[25];
  const void* bf_Wv  = d_in[26];
  const void* bf_Wsh = d_in[27];
  const void* bf_Wr  = d_in[28];
  const void* bf_Wo  = d_in[29];
  const void* bf_F1  = d_in[30];
  const void* bf_F2  = d_in[31];
  const void* hW1    = d_in[32];
  const void* hW2    = d_in[33];

  char* bws = (char*)d_ws;
  size_t off = 0;
  auto alloc = [&](size_t bytes) -> void* {
    void* p = bws + off;
    off += (bytes + 255) & ~(size_t)255;
    return p;
  };
  int* dflag   = (int*)alloc(256);
  float* sh_f  = (float*)alloc((size_t)NE*9*4);
  float* t9    = (float*)alloc((size_t)NE*9*4);
  int* counts  = (int*)alloc(2048*4);
  int* rowptr  = (int*)alloc(2049*4);
  int* cursor  = (int*)alloc(2048*4);
  int* perm    = (int*)alloc((size_t)NE*4);
  float* injb  = (float*)alloc((size_t)NN*DINJ*4);
  float* zA    = (float*)alloc((size_t)NN*512*4);
  float* zB    = (float*)alloc((size_t)NN*512*4);
  ushort_t* xlnh = (ushort_t*)alloc((size_t)NN*736*2);
  float* qkvb  = (float*)alloc((size_t)NN*1440*4);
  float* Wr_all = (float*)alloc((size_t)128*24*4);
  float* r_all = (float*)alloc((size_t)6*NE*4*4);
  ushort_t* aggh = (ushort_t*)alloc((size_t)NN*DEMB*2);
  float* ybuf  = (float*)alloc((size_t)NN*720*4);
  ushort_t* h1h = (ushort_t*)alloc((size_t)NN*DEMB*2);
  ushort_t* g1h = (ushort_t*)alloc((size_t)NN*DFEAT*2);
  float* gsum  = (float*)alloc(64*4);

  float* pos_c    = (float*)alloc((size_t)NN*3*4);
  float* atom_c   = (float*)alloc((size_t)64*DINJ*4);
  float* degWr_c  = (float*)alloc((size_t)128*9*4);
  float* degWsh_c = (float*)alloc((size_t)9*DINJ*4);
  float* b0_Wsh_c = (float*)alloc((size_t)9*480*4);
  float* b0_Wr_c  = (float*)alloc((size_t)128*4*4);
  float* bm_Wsh_c = (float*)alloc((size_t)4*9*480*4);
  float* bm_Wr_c  = (float*)alloc((size_t)4*128*4*4);
  float* bf_Wsh_c = (float*)alloc((size_t)9*480*4);
  float* bf_Wr_c  = (float*)alloc((size_t)128*4*4);
  float* hW2_c    = (float*)alloc((size_t)512*4);

  auto allocW = [&](size_t elems, ushort_t*& h, ushort_t*& l){
    h = (ushort_t*)alloc(elems*2); l = (ushort_t*)alloc(elems*2);
  };
  ushort_t *b0_qkvTh,*b0_qkvTl,*b0_WoTh,*b0_WoTl,*b0_F1Th,*b0_F1Tl,*b0_F2Th,*b0_F2Tl;
  allocW((size_t)1472*736, b0_qkvTh, b0_qkvTl);
  allocW((size_t)768*480,  b0_WoTh,  b0_WoTl);
  allocW((size_t)512*736,  b0_F1Th,  b0_F1Tl);
  allocW((size_t)512*480,  b0_F2Th,  b0_F2Tl);
  ushort_t *bm_qkvTh[4],*bm_qkvTl[4],*bm_WoTh[4],*bm_WoTl[4],*bm_F1Th[4],*bm_F1Tl[4],*bm_F2Th[4],*bm_F2Tl[4];
  for (int i = 0; i < 4; ++i){
    allocW((size_t)1472*480, bm_qkvTh[i], bm_qkvTl[i]);
    allocW((size_t)512*480,  bm_WoTh[i],  bm_WoTl[i]);
    allocW((size_t)512*480,  bm_F1Th[i],  bm_F1Tl[i]);
    allocW((size_t)512*480,  bm_F2Th[i],  bm_F2Tl[i]);
  }
  ushort_t *bf_qkvTh,*bf_qkvTl,*bf_WoTh,*bf_WoTl,*bf_F1Th,*bf_F1Tl,*bf_F2Th,*bf_F2Tl,*hW1Th,*hW1Tl;
  allocW((size_t)1472*480, bf_qkvTh, bf_qkvTl);
  allocW((size_t)512*480,  bf_WoTh,  bf_WoTl);
  allocW((size_t)512*480,  bf_F1Th,  bf_F1Tl);
  allocW((size_t)512*480,  bf_F2Th,  bf_F2Tl);
  allocW((size_t)512*512,  hW1Th,    hW1Tl);

  detect_kernel<<<1, 256, 0, stream>>>((const ushort_t*)atom_table, dflag);

  CDescArr ca;
  int ci = 0;
  auto addC = [&](const void* s, float* d, int n){
    ca.d[ci].src = s; ca.d[ci].dst = d; ca.d[ci].n = n; ++ci;
  };
  addC(pos, pos_c, NN*3);
  addC(atom_table, atom_c, 64*DINJ);
  addC(degWr, degWr_c, 128*9);
  addC(degWsh, degWsh_c, 9*DINJ);
  addC(b0_Wsh, b0_Wsh_c, 9*480);
  addC(b0_Wr, b0_Wr_c, 128*4);
  addC(bm_Wsh, bm_Wsh_c, 4*9*480);
  addC(bm_Wr, bm_Wr_c, 4*128*4);
  addC(bf_Wsh, bf_Wsh_c, 9*480);
  addC(bf_Wr, bf_Wr_c, 128*4);
  addC(hW2, hW2_c, 512);
  convert_inputs<<<dim3(8, 11), 256, 0, stream>>>(ca, dflag);

  TDescArr ta;
  int ti = 0;
  auto addT = [&](const void* s, ushort_t* dh, ushort_t* dl, int K, int M,
                  int Kp, int Mp, int rowoff, int eo){
    ta.d[ti].src = s;
    ta.d[ti].dh = dh + (size_t)rowoff*Kp;
    ta.d[ti].dl = dl + (size_t)rowoff*Kp;
    ta.d[ti].K = K; ta.d[ti].M = M; ta.d[ti].Kpad = Kp; ta.d[ti].Mpad = Mp;
    ta.d[ti].eoff = eo; ++ti;
  };
  addT(b0_Wq, b0_qkvTh, b0_qkvTl, 720, 480, 736, 480, 0,   0);
  addT(b0_Wk, b0_qkvTh, b0_qkvTl, 720, 480, 736, 480, 480, 0);
  addT(b0_Wv, b0_qkvTh, b0_qkvTl, 720, 480, 736, 512, 960, 0);
  addT(b0_Wo, b0_WoTh,  b0_WoTl,  480, 720, 480, 768, 0,   0);
  addT(b0_F1, b0_F1Th,  b0_F1Tl,  720, 480, 736, 512, 0,   0);
  addT(b0_F2, b0_F2Th,  b0_F2Tl,  480, 480, 480, 512, 0,   0);
  for (int i = 0; i < 4; ++i){
    int eo = i*480*480;
    addT(bm_Wq, bm_qkvTh[i], bm_qkvTl[i], 480, 480, 480, 480, 0,   eo);
    addT(bm_Wk, bm_qkvTh[i], bm_qkvTl[i], 480, 480, 480, 480, 480, eo);
    addT(bm_Wv, bm_qkvTh[i], bm_qkvTl[i], 480, 480, 480, 512, 960, eo);
    addT(bm_Wo, bm_WoTh[i],  bm_WoTl[i],  480, 480, 480, 512, 0,   eo);
    addT(bm_F1, bm_F1Th[i],  bm_F1Tl[i],  480, 480, 480, 512, 0,   eo);
    addT(bm_F2, bm_F2Th[i],  bm_F2Tl[i],  480, 480, 480, 512, 0,   eo);
  }
  addT(bf_Wq, bf_qkvTh, bf_qkvTl, 480, 480, 480, 480, 0,   0);
  addT(bf_Wk, bf_qkvTh, bf_qkvTl, 480, 480, 480, 480, 480, 0);
  addT(bf_Wv, bf_qkvTh, bf_qkvTl, 480, 480, 480, 512, 960, 0);
  addT(bf_Wo, bf_WoTh,  bf_WoTl,  480, 480, 480, 512, 0,   0);
  addT(bf_F1, bf_F1Th,  bf_F1Tl,  480, 480, 480, 512, 0,   0);
  addT(bf_F2, bf_F2Th,  bf_F2Tl,  480, 512, 480, 512, 0,   0);
  addT(hW1,   hW1Th,    hW1Tl,    512, 512, 512, 512, 0,   0);
  transpose_all<<<dim3(23, 24, 37), 256, 0, stream>>>(ta, dflag);

  pack_wr<<<12, 256, 0, stream>>>(b0_Wr_c, bm_Wr_c, bf_Wr_c, Wr_all);
  edge_all_kernel<<<NE/256, 256, 0, stream>>>(pos_c, esrc, edst, degWr_c, Wr_all,
                                              sh_f, t9, r_all);

  zero_f32<<<(2048 + 255)/256, 256, 0, stream>>>((float*)counts, 2048);
  hist_kernel<<<NE/256, 256, 0, stream>>>(edst, counts);
  scan_kernel<<<1, 1024, 0, stream>>>(counts, rowptr, cursor);
  scatter_kernel<<<NE/256, 256, 0, stream>>>(edst, cursor, perm);

  inj_kernel<<<NN, 64, 0, stream>>>(t9, rowptr, perm, node_atom, atom_c, degWsh_c, injb);
  zero_f32<<<(NN*DEMB)/256, 256, 0, stream>>>(zA, NN*DEMB);

  auto gemm = [&](const ushort_t* A, const ushort_t* BTh, const ushort_t* BTl,
                  int N, int Npad, int Kp, int ldc,
                  float* Cf, ushort_t* Cb, const float* R, const float* R2,
                  int flags, bool split){
    dim3 g(Npad/64, 32);
    if (split){
      if (Kp == 480)
        gemm_bt<480,true><<<g, 256, 0, stream>>>(A, BTh, BTl, N, ldc, Cf, Cb, R, R2, flags);
      else if (Kp == 512)
        gemm_bt<512,true><<<g, 256, 0, stream>>>(A, BTh, BTl, N, ldc, Cf, Cb, R, R2, flags);
      else
        gemm_bt<736,true><<<g, 256, 0, stream>>>(A, BTh, BTl, N, ldc, Cf, Cb, R, R2, flags);
    } else {
      if (Kp == 480)
        gemm_bt<480,false><<<g, 256, 0, stream>>>(A, BTh, BTl, N, ldc, Cf, Cb, R, R2, flags);
      else if (Kp == 512)
        gemm_bt<512,false><<<g, 256, 0, stream>>>(A, BTh, BTl, N, ldc, Cf, Cb, R, R2, flags);
      else
        gemm_bt<736,false><<<g, 256, 0, stream>>>(A, BTh, BTl, N, ldc, Cf, Cb, R, R2, flags);
    }
  };

  struct BW {
    const float *Wsh, *r_slot;
    const ushort_t *qkvTh,*qkvTl,*WoTh,*WoTl,*F1Th,*F1Tl,*F2Th,*F2Tl;
    int Din, Kpad, Dout; bool res;
  };
  // zinj != null -> input is concat [zin(480) | zinj(240)] (b0 blocks)
  auto run_block = [&](const BW& bw, const float* zin, const float* zinj, float* zout){
    if (zinj) ln_cat_kernel<<<NN/4, 256, 0, stream>>>(zin, zinj, xlnh);
    else      ln_kernel<<<NN/4, 256, 0, stream>>>(zin, bw.Din, bw.Kpad, xlnh);
    gemm(xlnh, bw.qkvTh, bw.qkvTl, 1440, 1472, bw.Kpad, 1440,
         qkvb, nullptr, nullptr, nullptr, 0, true);
    node_attn_kernel<<<NN, 256, 0, stream>>>(qkvb, sh_f, bw.Wsh, bw.r_slot,
                                             rowptr, perm, esrc, aggh);
    int WoNpad = (bw.Din == 720) ? 768 : 512;
    gemm(aggh, bw.WoTh, bw.WoTl, bw.Din, WoNpad, 480, bw.Din,
         ybuf, nullptr, zin, zinj, zinj ? (2|8) : 2, false);
    ln_kernel<<<NN/4, 256, 0, stream>>>(ybuf, bw.Din, bw.Kpad, xlnh);
    gemm(xlnh, bw.F1Th, bw.F1Tl, DEMB, 512, bw.Kpad, DEMB,
         nullptr, h1h, nullptr, nullptr, 1|4, false);
    gemm(h1h, bw.F2Th, bw.F2Tl, bw.Dout, 512, 480, bw.Dout,
         zout, nullptr, bw.res ? ybuf : nullptr, nullptr, bw.res ? 2 : 0, false);
  };

  BW b0 = { b0_Wsh_c, r_all + (size_t)0*NE*4,
            b0_qkvTh,b0_qkvTl,b0_WoTh,b0_WoTl,b0_F1Th,b0_F1Tl,b0_F2Th,b0_F2Tl,
            720, 736, 480, false };
  BW bm[4];
  for (int i = 0; i < 4; ++i){
    bm[i] = { bm_Wsh_c + (size_t)i*9*480, r_all + (size_t)(1+i)*NE*4,
              bm_qkvTh[i],bm_qkvTl[i],bm_WoTh[i],bm_WoTl[i],
              bm_F1Th[i],bm_F1Tl[i],bm_F2Th[i],bm_F2Tl[i],
              480, 480, 480, true };
  }
  BW bf = { bf_Wsh_c, r_all + (size_t)5*NE*4,
            bf_qkvTh,bf_qkvTl,bf_WoTh,bf_WoTl,bf_F1Th,bf_F1Tl,bf_F2Th,bf_F2Tl,
            480, 480, 512, false };

  float* z  = zA;
  float* z2 = zB;
  for (int iter = 0; iter < 2; ++iter){
    run_block(b0, z, injb, z2);
    { float* tmp = z; z = z2; z2 = tmp; }
    for (int i = 0; i < 4; ++i){
      run_block(bm[i], z, nullptr, z2);
      { float* tmp = z; z = z2; z2 = tmp; }
    }
  }
  run_block(bf, z, nullptr, z2);
  ln_kernel<<<NN/4, 256, 0, stream>>>(z2, DFEAT, DFEAT, xlnh);
  gemm(xlnh, hW1Th, hW1Tl, DFEAT, 512, DFEAT, DFEAT,
       nullptr, g1h, nullptr, nullptr, 1|4, true);
  zero_f32<<<1, 64, 0, stream>>>(gsum, 64);
  head_dot_kernel<<<NN/4, 256, 0, stream>>>(g1h, hW2_c, batch, gsum);
  finalize_kernel<<<1, 64, 0, stream>>>(gsum, dflag, d_out);
}

// Round 16
// 1385.612 us; speedup vs baseline: 1.1798x; 1.0159x over previous
//
#include <hip/hip_runtime.h>

#define NN 2048
#define NE 32768
#define NG 64
#define DINJ 240
#define DEMB 480
#define DFEAT 512
#define MAXDEG 192

typedef unsigned short ushort_t;
typedef __attribute__((ext_vector_type(8))) short short8;
typedef __attribute__((ext_vector_type(4))) float floatx4;

__device__ __forceinline__ float b2f(ushort_t u){
  union { unsigned u; float f; } x; x.u = ((unsigned)u) << 16; return x.f;
}
__device__ __forceinline__ ushort_t f2b(float f){
  union { float f; unsigned u; } x; x.f = f;
  unsigned r = x.u + 0x7FFFu + ((x.u >> 16) & 1u);
  return (ushort_t)(r >> 16);
}
__device__ __forceinline__ float wredsum(float v){
  #pragma unroll
  for (int o = 32; o > 0; o >>= 1) v += __shfl_xor(v, o, 64);
  return v;
}
__device__ __forceinline__ float silu_f(float x){ return x / (1.f + __expf(-x)); }

// ---------------- small utility kernels ----------------
__global__ void zero_f32(float* p, int n){
  int i = blockIdx.x*256 + threadIdx.x; if (i < n) p[i] = 0.f;
}

// ---------------- input dtype detection ----------------
__global__ void detect_kernel(const ushort_t* __restrict__ probe, int* flag){
  __shared__ int c;
  if (threadIdx.x == 0) c = 0;
  __syncthreads();
  ushort_t u = probe[2*threadIdx.x];
  int e = (u >> 7) & 0xFF;
  int plausible = (u == 0) || (e >= 100 && e <= 140);
  atomicAdd(&c, plausible);
  __syncthreads();
  if (threadIdx.x == 0) *flag = (c >= 192) ? 0 : 1;
}

// -------- convert small float inputs -> internal FP32 (exact either way) ----
struct CDesc { const void* src; float* dst; int n; };
struct CDescArr { CDesc d[11]; };
__global__ __launch_bounds__(256) void convert_inputs(CDescArr ca, const int* __restrict__ flag){
  CDesc cd = ca.d[blockIdx.y];
  int isf32 = *flag;
  for (int i = blockIdx.x*256 + threadIdx.x; i < cd.n; i += gridDim.x*256){
    cd.dst[i] = isf32 ? ((const float*)cd.src)[i] : b2f(((const ushort_t*)cd.src)[i]);
  }
}

// --- LDS-tiled weight transpose: src (K x M row-major) -> dst (Mpad x Kpad) --
struct TDesc { const void* src; ushort_t* dh; ushort_t* dl; int K; int M; int Kpad; int Mpad; int eoff; };
struct TDescArr { TDesc d[37]; };
__global__ __launch_bounds__(256) void transpose_all(TDescArr ta, const int* __restrict__ flag){
  TDesc td = ta.d[blockIdx.z];
  int k0 = blockIdx.x*32, m0 = blockIdx.y*32;
  if (k0 >= td.Kpad || m0 >= td.Mpad) return;
  int isf32 = *flag;
  __shared__ float lds[32*33];
  int tx = threadIdx.x & 31, ty = threadIdx.x >> 5;
  #pragma unroll
  for (int r = 0; r < 4; ++r){
    int kl = ty + r*8;
    int k = k0 + kl, mm = m0 + tx;
    float x = 0.f;
    if (k < td.K && mm < td.M){
      size_t si = (size_t)td.eoff + (size_t)k*td.M + mm;
      x = isf32 ? ((const float*)td.src)[si] : b2f(((const ushort_t*)td.src)[si]);
    }
    lds[kl*33 + tx] = x;
  }
  __syncthreads();
  #pragma unroll
  for (int r = 0; r < 4; ++r){
    int nl = ty + r*8;
    int n = m0 + nl, k = k0 + tx;
    if (n < td.Mpad && k < td.Kpad){
      float x = lds[tx*33 + nl];
      ushort_t h = f2b(x);
      size_t di = (size_t)n*td.Kpad + k;
      td.dh[di] = h;
      td.dl[di] = f2b(x - b2f(h));
    }
  }
}

// ---- pack 6 Wr slots into Wr_all[128][24] (k-major, o=slot*4+h inner) ------
__global__ void pack_wr(const float* __restrict__ b0Wr, const float* __restrict__ bmWr,
                        const float* __restrict__ bfWr, float* __restrict__ Wr_all){
  int idx = blockIdx.x*256 + threadIdx.x; if (idx >= 128*24) return;
  int k = idx / 24, o = idx - k*24;
  int slot = o >> 2, h = o & 3;
  const float* Wr = (slot == 0) ? b0Wr : ((slot <= 4) ? bmWr + (size_t)(slot-1)*512 : bfWr);
  Wr_all[idx] = Wr[k*4+h];
}

// ---- fused per-edge setup: LDS-staged weights, 128-thread blocks ------------
__global__ __launch_bounds__(128) void edge_all_kernel(
    const float* __restrict__ pos,
    const int* __restrict__ esrc, const int* __restrict__ edst,
    const float* __restrict__ degWr, const float* __restrict__ Wr_all,
    float* __restrict__ sh_out, float* __restrict__ t9,
    float* __restrict__ r_all){
  __shared__ float w9L[128*9];
  __shared__ float w24L[128*24];
  int t = threadIdx.x;
  for (int i = t; i < 128*9; i += 128)  w9L[i]  = degWr[i];
  for (int i = t; i < 128*24; i += 128) w24L[i] = Wr_all[i];
  __syncthreads();
  int e = blockIdx.x*128 + t; if (e >= NE) return;
  int s = esrc[e], d = edst[e];
  float x = pos[s*3+0] - pos[d*3+0];
  float y = pos[s*3+1] - pos[d*3+1];
  float z = pos[s*3+2] - pos[d*3+2];
  float dd = sqrtf(x*x + y*y + z*z + 1e-12f);
  float ix = x/dd, iy = y/dd, iz = z/dd;
  const float s3 = 1.7320508075688772f, s15 = 3.872983346207417f, s5 = 2.23606797749979f;
  float sh[9];
  sh[0] = 1.f; sh[1] = s3*ix; sh[2] = s3*iy; sh[3] = s3*iz;
  sh[4] = s15*ix*iy; sh[5] = s15*iy*iz; sh[6] = 0.5f*s5*(3.f*iz*iz - 1.f);
  sh[7] = s15*ix*iz; sh[8] = 0.5f*s15*(ix*ix - iy*iy);
  #pragma unroll
  for (int j = 0; j < 9; ++j) sh_out[(size_t)e*9+j] = sh[j];
  float t9a[9], ga[24];
  #pragma unroll
  for (int j = 0; j < 9; ++j) t9a[j] = 0.f;
  #pragma unroll
  for (int o = 0; o < 24; ++o) ga[o] = 0.f;
  for (int k = 0; k < 128; ++k){
    float c = (float)k * (5.0f/127.0f);
    float u = (dd - c) * (128.0f/5.0f);
    float rb = __expf(-0.5f*u*u);
    const float* w9  = w9L + k*9;
    const float* w24 = w24L + k*24;
    #pragma unroll
    for (int j = 0; j < 9; ++j) t9a[j] += rb*w9[j];
    #pragma unroll
    for (int o = 0; o < 24; ++o) ga[o] += rb*w24[o];
  }
  #pragma unroll
  for (int j = 0; j < 9; ++j) t9[(size_t)e*9+j] = sh[j]*silu_f(t9a[j]);
  #pragma unroll
  for (int o = 0; o < 24; ++o){
    int slot = o >> 2, h = o & 3;
    r_all[((size_t)slot*NE + e)*4 + h] = silu_f(ga[o]);
  }
}

// ---------------- CSR build ----------------
__global__ void hist_kernel(const int* __restrict__ edst, int* counts){
  int e = blockIdx.x*256 + threadIdx.x; if (e < NE) atomicAdd(&counts[edst[e]], 1);
}
__global__ __launch_bounds__(1024) void scan_kernel(const int* __restrict__ counts,
                                                    int* rowptr, int* cursor){
  __shared__ int s[1024];
  int t = threadIdx.x;
  int c0 = counts[2*t], c1 = counts[2*t+1];
  s[t] = c0 + c1;
  __syncthreads();
  for (int off = 1; off < 1024; off <<= 1){
    int v = (t >= off) ? s[t-off] : 0;
    __syncthreads();
    s[t] += v;
    __syncthreads();
  }
  int excl = s[t] - (c0 + c1);
  rowptr[2*t]   = excl;       cursor[2*t]   = excl;
  rowptr[2*t+1] = excl + c0;  cursor[2*t+1] = excl + c0;
  if (t == 1023) rowptr[2048] = s[1023];
}
__global__ void scatter_kernel(const int* __restrict__ edst, int* cursor, int* perm){
  int e = blockIdx.x*256 + threadIdx.x; if (e >= NE) return;
  int p = atomicAdd(&cursor[edst[e]], 1);
  perm[p] = e;
}

// ---------------- inj = atom_table[node_atom] + (sum_e t9) @ degWsh / 16 -----
__global__ __launch_bounds__(64) void inj_kernel(const float* __restrict__ t9,
    const int* __restrict__ rowptr, const int* __restrict__ perm,
    const int* __restrict__ node_atom, const float* __restrict__ atom_table,
    const float* __restrict__ degWsh, float* __restrict__ inj){
  int i = blockIdx.x; int lane = threadIdx.x;
  int b = rowptr[i], e = rowptr[i+1];
  float T[9];
  #pragma unroll
  for (int j = 0; j < 9; ++j) T[j] = 0.f;
  for (int idx = b; idx < e; ++idx){
    int ed = perm[idx];
    #pragma unroll
    for (int j = 0; j < 9; ++j) T[j] += t9[(size_t)ed*9+j];
  }
  int a = node_atom[i];
  for (int c = lane; c < DINJ; c += 64){
    float s = 0.f;
    #pragma unroll
    for (int j = 0; j < 9; ++j) s += T[j]*degWsh[j*DINJ+c];
    inj[(size_t)i*DINJ+c] = atom_table[(size_t)a*DINJ+c] + s*(1.0f/16.0f);
  }
}

// ------- LayerNorm: one wave per row, 4 rows per block -----------------------
__global__ __launch_bounds__(256) void ln_kernel(const float* __restrict__ in, int D,
                                                 int Kpad, ushort_t* __restrict__ oh){
  int i = blockIdx.x*4 + (threadIdx.x >> 6);
  int lane = threadIdx.x & 63;
  const float* row = in + (size_t)i*D;
  float s = 0.f, sq = 0.f;
  for (int d = lane; d < D; d += 64){ float x = row[d]; s += x; sq += x*x; }
  s = wredsum(s); sq = wredsum(sq);
  float mu = s / (float)D;
  float var = fmaxf(sq / (float)D - mu*mu, 0.f);
  float rs = rsqrtf(var + 1e-6f);
  ushort_t* ohrow = oh + (size_t)i*Kpad;
  for (int d = lane; d < D; d += 64) ohrow[d] = f2b((row[d]-mu)*rs);
  for (int d = D + lane; d < Kpad; d += 64) ohrow[d] = 0;
}

// ------- LayerNorm over concat [z(480) | inj(240)] -> 736-padded bf16 --------
__global__ __launch_bounds__(256) void ln_cat_kernel(const float* __restrict__ z,
    const float* __restrict__ inj, ushort_t* __restrict__ oh){
  int i = blockIdx.x*4 + (threadIdx.x >> 6);
  int lane = threadIdx.x & 63;
  const float* zr = z + (size_t)i*480;
  const float* ir = inj + (size_t)i*240;
  float s = 0.f, sq = 0.f;
  for (int d = lane; d < 720; d += 64){
    float x = (d < 480) ? zr[d] : ir[d-480];
    s += x; sq += x*x;
  }
  s = wredsum(s); sq = wredsum(sq);
  float mu = s * (1.0f/720.0f);
  float var = fmaxf(sq * (1.0f/720.0f) - mu*mu, 0.f);
  float rs = rsqrtf(var + 1e-6f);
  ushort_t* ohrow = oh + (size_t)i*736;
  for (int d = lane; d < 720; d += 64){
    float x = (d < 480) ? zr[d] : ir[d-480];
    ohrow[d] = f2b((x-mu)*rs);
  }
  for (int d = 720 + lane; d < 736; d += 64) ohrow[d] = 0;
}

// -- MFMA GEMM: C = A * B^T with B = Bh (+Bl if SPLITB). Ring prefetch. -------
// flags: 1=silu, 2=add residual, 4=bf16 out, 8=residual is concat(R 480, R2 240)
template<int KPAD, bool SPLITB>
__global__ __launch_bounds__(256) void gemm_bt(
    const ushort_t* __restrict__ A,
    const ushort_t* __restrict__ BTh, const ushort_t* __restrict__ BTl,
    int N, int ldc,
    float* __restrict__ Cf, ushort_t* __restrict__ Cb,
    const float* __restrict__ R, const float* __restrict__ R2, int flags){
  int lane = threadIdx.x & 63, wave = threadIdx.x >> 6;
  int row0 = blockIdx.y*64 + (wave>>1)*32;
  int col0 = blockIdx.x*64 + (wave&1)*32;
  int m = lane & 15, q4 = lane >> 4;
  size_t a0 = (size_t)(row0+m)*KPAD + q4*8;
  size_t a1 = a0 + (size_t)16*KPAD;
  size_t b0 = (size_t)(col0+m)*KPAD + q4*8;
  size_t b1 = b0 + (size_t)16*KPAD;
  floatx4 acc00 = {0,0,0,0}, acc01 = {0,0,0,0}, acc10 = {0,0,0,0}, acc11 = {0,0,0,0};
  constexpr int steps = KPAD >> 5;
  constexpr int DEPTH = SPLITB ? 3 : 4;
  struct Frag { short8 A0, A1, B0h, B1h, B0l, B1l; };
  auto loadF = [&](int s) -> Frag {
    Frag f;
    size_t o = (size_t)s*32;
    f.A0  = *(const short8*)(A   + a0 + o);
    f.A1  = *(const short8*)(A   + a1 + o);
    f.B0h = *(const short8*)(BTh + b0 + o);
    f.B1h = *(const short8*)(BTh + b1 + o);
    if (SPLITB){
      f.B0l = *(const short8*)(BTl + b0 + o);
      f.B1l = *(const short8*)(BTl + b1 + o);
    }
    return f;
  };
  Frag ring[DEPTH];
  #pragma unroll
  for (int d = 0; d < DEPTH; ++d) ring[d] = loadF(d < steps ? d : steps-1);
  #pragma unroll
  for (int s = 0; s < steps; ++s){
    Frag cur = ring[s % DEPTH];
    if (s + DEPTH < steps) ring[s % DEPTH] = loadF(s + DEPTH);
    acc00 = __builtin_amdgcn_mfma_f32_16x16x32_bf16(cur.A0, cur.B0h, acc00, 0, 0, 0);
    acc01 = __builtin_amdgcn_mfma_f32_16x16x32_bf16(cur.A0, cur.B1h, acc01, 0, 0, 0);
    acc10 = __builtin_amdgcn_mfma_f32_16x16x32_bf16(cur.A1, cur.B0h, acc10, 0, 0, 0);
    acc11 = __builtin_amdgcn_mfma_f32_16x16x32_bf16(cur.A1, cur.B1h, acc11, 0, 0, 0);
    if (SPLITB){
      acc00 = __builtin_amdgcn_mfma_f32_16x16x32_bf16(cur.A0, cur.B0l, acc00, 0, 0, 0);
      acc01 = __builtin_amdgcn_mfma_f32_16x16x32_bf16(cur.A0, cur.B1l, acc01, 0, 0, 0);
      acc10 = __builtin_amdgcn_mfma_f32_16x16x32_bf16(cur.A1, cur.B0l, acc10, 0, 0, 0);
      acc11 = __builtin_amdgcn_mfma_f32_16x16x32_bf16(cur.A1, cur.B1l, acc11, 0, 0, 0);
    }
  }
  #pragma unroll
  for (int rr = 0; rr < 2; ++rr){
    #pragma unroll
    for (int cc = 0; cc < 2; ++cc){
      int col = col0 + cc*16 + m;
      if (col >= N) continue;
      floatx4 acc = rr ? (cc ? acc11 : acc10) : (cc ? acc01 : acc00);
      int rowb = row0 + rr*16 + q4*4;
      #pragma unroll
      for (int r = 0; r < 4; ++r){
        int row = rowb + r;
        size_t idx = (size_t)row*ldc + col;
        float v = acc[r];
        if (flags & 2){
          if (flags & 8)
            v += (col < 480) ? R[(size_t)row*480 + col] : R2[(size_t)row*240 + (col-480)];
          else
            v += R[idx];
        }
        if (flags & 1) v = silu_f(v);
        if (flags & 4) Cb[idx] = f2b(v);
        else           Cf[idx] = v;
      }
    }
  }
}

// ------- fused per-node attention: logits + softmax + aggregation ------------
__global__ __launch_bounds__(256) void node_attn_kernel(
    const float* __restrict__ qkv, const float* __restrict__ sh,
    const float* __restrict__ Wsh, const float* __restrict__ r_slot,
    const int* __restrict__ rowptr, const int* __restrict__ perm,
    const int* __restrict__ esrc, ushort_t* __restrict__ aggh){
  int i = blockIdx.x; int t = threadIdx.x;
  int lane = t & 63, w = t >> 6;
  int b = rowptr[i]; int deg = min(rowptr[i+1] - b, MAXDEG);
  __shared__ float qL[480];
  __shared__ float PqL[36];
  __shared__ float logitL[MAXDEG*4];
  __shared__ float rL[MAXDEG*4];
  __shared__ int eL[MAXDEG], srcL[MAXDEG];
  __shared__ float S[36];
  __shared__ float mxs[4], dens[4];
  for (int d = t; d < 480; d += 256) qL[d] = qkv[(size_t)i*1440 + d];
  for (int idx = t; idx < deg; idx += 256){
    int e = perm[b+idx];
    eL[idx] = e;
    srcL[idx] = esrc[e];
  }
  __syncthreads();
  if (t < 36){
    int h = t/9, j = t - h*9;
    const float* ws = Wsh + (size_t)j*DEMB + h*120;
    const float* qh = qL + h*120;
    float p = 0.f;
    for (int k = 0; k < 120; ++k) p += qh[k]*ws[k];
    PqL[t] = p;
  }
  __syncthreads();
  const float inv = 0.091287092917527686f;
  for (int base = 0; base < deg; base += 64){
    int idx = base + (t >> 2);
    if (idx < deg){
      int h = t & 3;
      int e = eL[idx], s = srcL[idx];
      const float4* kk = (const float4*)(qkv + (size_t)s*1440 + 480 + h*120);
      const float4* qq = (const float4*)(qL + h*120);
      float p = 0.f;
      #pragma unroll
      for (int it = 0; it < 30; ++it){
        float4 a = qq[it], bb = kk[it];
        p += a.x*bb.x + a.y*bb.y + a.z*bb.z + a.w*bb.w;
      }
      float mmq = 0.f;
      const float* she = sh + (size_t)e*9;
      #pragma unroll
      for (int j = 0; j < 9; ++j) mmq += she[j]*PqL[h*9+j];
      float rr = r_slot[(size_t)e*4+h];
      rL[idx*4+h] = rr;
      logitL[idx*4+h] = rr*(p + mmq)*inv;
    }
  }
  __syncthreads();
  float mx = -1e30f;
  for (int idx = lane; idx < deg; idx += 64) mx = fmaxf(mx, logitL[idx*4+w]);
  #pragma unroll
  for (int o = 32; o > 0; o >>= 1) mx = fmaxf(mx, __shfl_xor(mx, o, 64));
  if (deg == 0) mx = 0.f;
  float den = 0.f;
  for (int idx = lane; idx < deg; idx += 64) den += __expf(logitL[idx*4+w]-mx);
  den = wredsum(den) + 1e-9f;
  if (lane == 0){ mxs[w] = mx; dens[w] = den; }
  __syncthreads();
  for (int j = t; j < deg*4; j += 256){
    int h = j & 3;
    logitL[j] = __expf(logitL[j]-mxs[h]) / dens[h] * rL[j];
  }
  __syncthreads();
  float a0 = 0.f, a1 = 0.f;
  int d0 = 2*t, h2 = d0/120;
  if (t >= 240){
    for (int o = t - 240; o < 36; o += 16){
      int h = o/9, j = o - h*9;
      float a = 0.f;
      for (int idx = 0; idx < deg; ++idx)
        a += logitL[idx*4+h]*sh[(size_t)eL[idx]*9+j];
      S[o] = a;
    }
  } else {
    for (int idx = 0; idx < deg; ++idx){
      float wgt = logitL[idx*4+h2];
      float2 vv = *(const float2*)(qkv + (size_t)srcL[idx]*1440 + 960 + d0);
      a0 += wgt*vv.x; a1 += wgt*vv.y;
    }
  }
  __syncthreads();
  if (t < 240){
    float mm0 = 0.f, mm1 = 0.f;
    #pragma unroll
    for (int j = 0; j < 9; ++j){
      mm0 += S[h2*9+j]*Wsh[j*DEMB + d0];
      mm1 += S[h2*9+j]*Wsh[j*DEMB + d0 + 1];
    }
    aggh[(size_t)i*DEMB + d0]     = f2b(a0 + mm0);
    aggh[(size_t)i*DEMB + d0 + 1] = f2b(a1 + mm1);
  }
}

// ---------------- head ----------------
__global__ __launch_bounds__(256) void head_dot_kernel(const ushort_t* __restrict__ g1h,
    const float* __restrict__ hW2, const int* __restrict__ batch, float* gsum){
  int i = blockIdx.x*4 + (threadIdx.x >> 6);
  int lane = threadIdx.x & 63;
  float s = 0.f;
  for (int d = lane; d < DFEAT; d += 64)
    s += b2f(g1h[(size_t)i*DFEAT + d]) * hW2[d];
  s = wredsum(s);
  if (lane == 0) atomicAdd(&gsum[batch[i]], s);
}
__global__ void finalize_kernel(const float* __restrict__ gsum,
                                const int* __restrict__ flag, void* out){
  int g = threadIdx.x;
  if (g < NG){
    float v = gsum[g] * 0.17677669529663687f; // 1/sqrt(32)
    if (*flag) ((float*)out)[g] = v;
    else       ((ushort_t*)out)[g] = f2b(v);
  }
}

// =====================================================================
extern "C" void kernel_launch(void* const* d_in, const int* in_sizes, int n_in,
                              void* d_out, int out_size, void* d_ws, size_t ws_size,
                              hipStream_t stream) {
  (void)in_sizes; (void)n_in; (void)out_size; (void)ws_size;
  const void* pos        = d_in[0];
  const int*  node_atom  = (const int*)d_in[1];
  const int*  esrc       = (const int*)d_in[2];
  const int*  edst       = (const int*)d_in[3];
  const int*  batch      = (const int*)d_in[4];
  const void* atom_table = d_in[5];
  const void* degWr      = d_in[6];
  const void* degWsh     = d_in[7];
  const void* b0_Wq  = d_in[8];
  const void* b0_Wk  = d_in[9];
  const void* b0_Wv  = d_in[10];
  const void* b0_Wsh = d_in[11];
  const void* b0_Wr  = d_in[12];
  const void* b0_Wo  = d_in[13];
  const void* b0_F1  = d_in[14];
  const void* b0_F2  = d_in[15];
  const void* bm_Wq  = d_in[16];
  const void* bm_Wk  = d_in[17];
  const void* bm_Wv  = d_in[18];
  const void* bm_Wsh = d_in[19];
  const void* bm_Wr  = d_in[20];
  const void* bm_Wo  = d_in[21];
  const void* bm_F1  = d_in[22];
  const void* bm_F2  = d_in[23];
  const void* bf_Wq  = d_in[24];
  const void* bf_Wk  = d_in[25];
  const void* bf_Wv  = d_in[26];
  const void* bf_Wsh = d_in[27];
  const void* bf_Wr  = d_in[28];
  const void* bf_Wo  = d_in[29];
  const void* bf_F1  = d_in[30];
  const void* bf_F2  = d_in[31];
  const void* hW1    = d_in[32];
  const void* hW2    = d_in[33];

  char* bws = (char*)d_ws;
  size_t off = 0;
  auto alloc = [&](size_t bytes) -> void* {
    void* p = bws + off;
    off += (bytes + 255) & ~(size_t)255;
    return p;
  };
  int* dflag   = (int*)alloc(256);
  float* sh_f  = (float*)alloc((size_t)NE*9*4);
  float* t9    = (float*)alloc((size_t)NE*9*4);
  int* counts  = (int*)alloc(2048*4);
  int* rowptr  = (int*)alloc(2049*4);
  int* cursor  = (int*)alloc(2048*4);
  int* perm    = (int*)alloc((size_t)NE*4);
  float* injb  = (float*)alloc((size_t)NN*DINJ*4);
  float* zA    = (float*)alloc((size_t)NN*512*4);
  float* zB    = (float*)alloc((size_t)NN*512*4);
  ushort_t* xlnh = (ushort_t*)alloc((size_t)NN*736*2);
  float* qkvb  = (float*)alloc((size_t)NN*1440*4);
  float* Wr_all = (float*)alloc((size_t)128*24*4);
  float* r_all = (float*)alloc((size_t)6*NE*4*4);
  ushort_t* aggh = (ushort_t*)alloc((size_t)NN*DEMB*2);
  float* ybuf  = (float*)alloc((size_t)NN*720*4);
  ushort_t* h1h = (ushort_t*)alloc((size_t)NN*DEMB*2);
  ushort_t* g1h = (ushort_t*)alloc((size_t)NN*DFEAT*2);
  float* gsum  = (float*)alloc(64*4);

  float* pos_c    = (float*)alloc((size_t)NN*3*4);
  float* atom_c   = (float*)alloc((size_t)64*DINJ*4);
  float* degWr_c  = (float*)alloc((size_t)128*9*4);
  float* degWsh_c = (float*)alloc((size_t)9*DINJ*4);
  float* b0_Wsh_c = (float*)alloc((size_t)9*480*4);
  float* b0_Wr_c  = (float*)alloc((size_t)128*4*4);
  float* bm_Wsh_c = (float*)alloc((size_t)4*9*480*4);
  float* bm_Wr_c  = (float*)alloc((size_t)4*128*4*4);
  float* bf_Wsh_c = (float*)alloc((size_t)9*480*4);
  float* bf_Wr_c  = (float*)alloc((size_t)128*4*4);
  float* hW2_c    = (float*)alloc((size_t)512*4);

  auto allocW = [&](size_t elems, ushort_t*& h, ushort_t*& l){
    h = (ushort_t*)alloc(elems*2); l = (ushort_t*)alloc(elems*2);
  };
  ushort_t *b0_qkvTh,*b0_qkvTl,*b0_WoTh,*b0_WoTl,*b0_F1Th,*b0_F1Tl,*b0_F2Th,*b0_F2Tl;
  allocW((size_t)1472*736, b0_qkvTh, b0_qkvTl);
  allocW((size_t)768*480,  b0_WoTh,  b0_WoTl);
  allocW((size_t)512*736,  b0_F1Th,  b0_F1Tl);
  allocW((size_t)512*480,  b0_F2Th,  b0_F2Tl);
  ushort_t *bm_qkvTh[4],*bm_qkvTl[4],*bm_WoTh[4],*bm_WoTl[4],*bm_F1Th[4],*bm_F1Tl[4],*bm_F2Th[4],*bm_F2Tl[4];
  for (int i = 0; i < 4; ++i){
    allocW((size_t)1472*480, bm_qkvTh[i], bm_qkvTl[i]);
    allocW((size_t)512*480,  bm_WoTh[i],  bm_WoTl[i]);
    allocW((size_t)512*480,  bm_F1Th[i],  bm_F1Tl[i]);
    allocW((size_t)512*480,  bm_F2Th[i],  bm_F2Tl[i]);
  }
  ushort_t *bf_qkvTh,*bf_qkvTl,*bf_WoTh,*bf_WoTl,*bf_F1Th,*bf_F1Tl,*bf_F2Th,*bf_F2Tl,*hW1Th,*hW1Tl;
  allocW((size_t)1472*480, bf_qkvTh, bf_qkvTl);
  allocW((size_t)512*480,  bf_WoTh,  bf_WoTl);
  allocW((size_t)512*480,  bf_F1Th,  bf_F1Tl);
  allocW((size_t)512*480,  bf_F2Th,  bf_F2Tl);
  allocW((size_t)512*512,  hW1Th,    hW1Tl);

  detect_kernel<<<1, 256, 0, stream>>>((const ushort_t*)atom_table, dflag);

  CDescArr ca;
  int ci = 0;
  auto addC = [&](const void* s, float* d, int n){
    ca.d[ci].src = s; ca.d[ci].dst = d; ca.d[ci].n = n; ++ci;
  };
  addC(pos, pos_c, NN*3);
  addC(atom_table, atom_c, 64*DINJ);
  addC(degWr, degWr_c, 128*9);
  addC(degWsh, degWsh_c, 9*DINJ);
  addC(b0_Wsh, b0_Wsh_c, 9*480);
  addC(b0_Wr, b0_Wr_c, 128*4);
  addC(bm_Wsh, bm_Wsh_c, 4*9*480);
  addC(bm_Wr, bm_Wr_c, 4*128*4);
  addC(bf_Wsh, bf_Wsh_c, 9*480);
  addC(bf_Wr, bf_Wr_c, 128*4);
  addC(hW2, hW2_c, 512);
  convert_inputs<<<dim3(8, 11), 256, 0, stream>>>(ca, dflag);

  TDescArr ta;
  int ti = 0;
  auto addT = [&](const void* s, ushort_t* dh, ushort_t* dl, int K, int M,
                  int Kp, int Mp, int rowoff, int eo){
    ta.d[ti].src = s;
    ta.d[ti].dh = dh + (size_t)rowoff*Kp;
    ta.d[ti].dl = dl + (size_t)rowoff*Kp;
    ta.d[ti].K = K; ta.d[ti].M = M; ta.d[ti].Kpad = Kp; ta.d[ti].Mpad = Mp;
    ta.d[ti].eoff = eo; ++ti;
  };
  addT(b0_Wq, b0_qkvTh, b0_qkvTl, 720, 480, 736, 480, 0,   0);
  addT(b0_Wk, b0_qkvTh, b0_qkvTl, 720, 480, 736, 480, 480, 0);
  addT(b0_Wv, b0_qkvTh, b0_qkvTl, 720, 480, 736, 512, 960, 0);
  addT(b0_Wo, b0_WoTh,  b0_WoTl,  480, 720, 480, 768, 0,   0);
  addT(b0_F1, b0_F1Th,  b0_F1Tl,  720, 480, 736, 512, 0,   0);
  addT(b0_F2, b0_F2Th,  b0_F2Tl,  480, 480, 480, 512, 0,   0);
  for (int i = 0; i < 4; ++i){
    int eo = i*480*480;
    addT(bm_Wq, bm_qkvTh[i], bm_qkvTl[i], 480, 480, 480, 480, 0,   eo);
    addT(bm_Wk, bm_qkvTh[i], bm_qkvTl[i], 480, 480, 480, 480, 480, eo);
    addT(bm_Wv, bm_qkvTh[i], bm_qkvTl[i], 480, 480, 480, 512, 960, eo);
    addT(bm_Wo, bm_WoTh[i],  bm_WoTl[i],  480, 480, 480, 512, 0,   eo);
    addT(bm_F1, bm_F1Th[i],  bm_F1Tl[i],  480, 480, 480, 512, 0,   eo);
    addT(bm_F2, bm_F2Th[i],  bm_F2Tl[i],  480, 480, 480, 512, 0,   eo);
  }
  addT(bf_Wq, bf_qkvTh, bf_qkvTl, 480, 480, 480, 480, 0,   0);
  addT(bf_Wk, bf_qkvTh, bf_qkvTl, 480, 480, 480, 480, 480, 0);
  addT(bf_Wv, bf_qkvTh, bf_qkvTl, 480, 480, 480, 512, 960, 0);
  addT(bf_Wo, bf_WoTh,  bf_WoTl,  480, 480, 480, 512, 0,   0);
  addT(bf_F1, bf_F1Th,  bf_F1Tl,  480, 480, 480, 512, 0,   0);
  addT(bf_F2, bf_F2Th,  bf_F2Tl,  480, 512, 480, 512, 0,   0);
  addT(hW1,   hW1Th,    hW1Tl,    512, 512, 512, 512, 0,   0);
  transpose_all<<<dim3(23, 24, 37), 256, 0, stream>>>(ta, dflag);

  pack_wr<<<12, 256, 0, stream>>>(b0_Wr_c, bm_Wr_c, bf_Wr_c, Wr_all);
  edge_all_kernel<<<NE/128, 128, 0, stream>>>(pos_c, esrc, edst, degWr_c, Wr_all,
                                              sh_f, t9, r_all);

  zero_f32<<<(2048 + 255)/256, 256, 0, stream>>>((float*)counts, 2048);
  hist_kernel<<<NE/256, 256, 0, stream>>>(edst, counts);
  scan_kernel<<<1, 1024, 0, stream>>>(counts, rowptr, cursor);
  scatter_kernel<<<NE/256, 256, 0, stream>>>(edst, cursor, perm);

  inj_kernel<<<NN, 64, 0, stream>>>(t9, rowptr, perm, node_atom, atom_c, degWsh_c, injb);
  zero_f32<<<(NN*DEMB)/256, 256, 0, stream>>>(zA, NN*DEMB);

  auto gemm = [&](const ushort_t* A, const ushort_t* BTh, const ushort_t* BTl,
                  int N, int Npad, int Kp, int ldc,
                  float* Cf, ushort_t* Cb, const float* R, const float* R2,
                  int flags, bool split){
    dim3 g(Npad/64, 32);
    if (split){
      if (Kp == 480)
        gemm_bt<480,true><<<g, 256, 0, stream>>>(A, BTh, BTl, N, ldc, Cf, Cb, R, R2, flags);
      else if (Kp == 512)
        gemm_bt<512,true><<<g, 256, 0, stream>>>(A, BTh, BTl, N, ldc, Cf, Cb, R, R2, flags);
      else
        gemm_bt<736,true><<<g, 256, 0, stream>>>(A, BTh, BTl, N, ldc, Cf, Cb, R, R2, flags);
    } else {
      if (Kp == 480)
        gemm_bt<480,false><<<g, 256, 0, stream>>>(A, BTh, BTl, N, ldc, Cf, Cb, R, R2, flags);
      else if (Kp == 512)
        gemm_bt<512,false><<<g, 256, 0, stream>>>(A, BTh, BTl, N, ldc, Cf, Cb, R, R2, flags);
      else
        gemm_bt<736,false><<<g, 256, 0, stream>>>(A, BTh, BTl, N, ldc, Cf, Cb, R, R2, flags);
    }
  };

  struct BW {
    const float *Wsh, *r_slot;
    const ushort_t *qkvTh,*qkvTl,*WoTh,*WoTl,*F1Th,*F1Tl,*F2Th,*F2Tl;
    int Din, Kpad, Dout; bool res;
  };
  auto run_block = [&](const BW& bw, const float* zin, const float* zinj, float* zout){
    if (zinj) ln_cat_kernel<<<NN/4, 256, 0, stream>>>(zin, zinj, xlnh);
    else      ln_kernel<<<NN/4, 256, 0, stream>>>(zin, bw.Din, bw.Kpad, xlnh);
    gemm(xlnh, bw.qkvTh, bw.qkvTl, 1440, 1472, bw.Kpad, 1440,
         qkvb, nullptr, nullptr, nullptr, 0, true);
    node_attn_kernel<<<NN, 256, 0, stream>>>(qkvb, sh_f, bw.Wsh, bw.r_slot,
                                             rowptr, perm, esrc, aggh);
    int WoNpad = (bw.Din == 720) ? 768 : 512;
    gemm(aggh, bw.WoTh, bw.WoTl, bw.Din, WoNpad, 480, bw.Din,
         ybuf, nullptr, zin, zinj, zinj ? (2|8) : 2, false);
    ln_kernel<<<NN/4, 256, 0, stream>>>(ybuf, bw.Din, bw.Kpad, xlnh);
    gemm(xlnh, bw.F1Th, bw.F1Tl, DEMB, 512, bw.Kpad, DEMB,
         nullptr, h1h, nullptr, nullptr, 1|4, false);
    gemm(h1h, bw.F2Th, bw.F2Tl, bw.Dout, 512, 480, bw.Dout,
         zout, nullptr, bw.res ? ybuf : nullptr, nullptr, bw.res ? 2 : 0, false);
  };

  BW b0 = { b0_Wsh_c, r_all + (size_t)0*NE*4,
            b0_qkvTh,b0_qkvTl,b0_WoTh,b0_WoTl,b0_F1Th,b0_F1Tl,b0_F2Th,b0_F2Tl,
            720, 736, 480, false };
  BW bm[4];
  for (int i = 0; i < 4; ++i){
    bm[i] = { bm_Wsh_c + (size_t)i*9*480, r_all + (size_t)(1+i)*NE*4,
              bm_qkvTh[i],bm_qkvTl[i],bm_WoTh[i],bm_WoTl[i],
              bm_F1Th[i],bm_F1Tl[i],bm_F2Th[i],bm_F2Tl[i],
              480, 480, 480, true };
  }
  BW bf = { bf_Wsh_c, r_all + (size_t)5*NE*4,
            bf_qkvTh,bf_qkvTl,bf_WoTh,bf_WoTl,bf_F1Th,bf_F1Tl,bf_F2Th,bf_F2Tl,
            480, 480, 512, false };

  float* z  = zA;
  float* z2 = zB;
  for (int iter = 0; iter < 2; ++iter){
    run_block(b0, z, injb, z2);
    { float* tmp = z; z = z2; z2 = tmp; }
    for (int i = 0; i < 4; ++i){
      run_block(bm[i], z, nullptr, z2);
      { float* tmp = z; z = z2; z2 = tmp; }
    }
  }
  run_block(bf, z, nullptr, z2);
  ln_kernel<<<NN/4, 256, 0, stream>>>(z2, DFEAT, DFEAT, xlnh);
  gemm(xlnh, hW1Th, hW1Tl, DFEAT, 512, DFEAT, DFEAT,
       nullptr, g1h, nullptr, nullptr, 1|4, true);
  zero_f32<<<1, 64, 0, stream>>>(gsum, 64);
  head_dot_kernel<<<NN/4, 256, 0, stream>>>(g1h, hW2_c, batch, gsum);
  finalize_kernel<<<1, 64, 0, stream>>>(gsum, dflag, d_out);
}